// Round 1
// baseline (1258.883 us; speedup 1.0000x reference)
//
#include <hip/hip_runtime.h>

// ---------------------------------------------------------------------------
// GraphUNet on MI355X.  N=4096, IN_C=128, HID=256, OUT_C=128, DEPTH=3,
// KS={2048,1024,512}.  All dims are multiples of 128 -> no GEMM bounds checks.
// ---------------------------------------------------------------------------

typedef __attribute__((ext_vector_type(8))) short bf16x8;
typedef __attribute__((ext_vector_type(4))) float f32x4;

__device__ __forceinline__ short f2bf(float f) {
    unsigned u = __builtin_bit_cast(unsigned, f);
    u += 0x7FFFu + ((u >> 16) & 1u);          // RNE
    return (short)(u >> 16);
}
__device__ __forceinline__ float bf2f(short s) {
    unsigned u = ((unsigned)(unsigned short)s) << 16;
    return __builtin_bit_cast(float, u);
}

#define KPAD 40   // LDS row stride (bf16 units) for 32-wide K tiles: 80B rows
                  // -> 16B-aligned ds_read_b128, 2-way bank aliasing (free)

// C = A(MxK) @ B(KxN), row-major fp32 in/out.
// MODE 0: hi*hi only        (exact when inputs are ints <= 256)
// MODE 1: hi*hi + hi*lo(B)  (A exact in bf16, B real-valued)
// MODE 2: + lo(A)*hi        (both real / large-int; drops lo*lo ~2^-17 rel)
// SPLITK: grid.z chunks over K, fp32 atomicAdd into pre-zeroed C.
template<int MODE, bool SPLITK>
__global__ __launch_bounds__(256, 2)
void gemm_tile(const float* __restrict__ Ag, const float* __restrict__ Bg,
               float* __restrict__ Cg, int M, int N, int K, int kChunk)
{
    __shared__ short Ah[128 * KPAD];
    __shared__ short Bh[128 * KPAD];
    __shared__ short Al[(MODE == 2) ? 128 * KPAD : 64];
    __shared__ short Bl[(MODE >= 1) ? 128 * KPAD : 64];

    const int t    = threadIdx.x;
    const int lane = t & 63;
    const int wave = t >> 6;
    const int tM   = blockIdx.y * 128;
    const int tN   = blockIdx.x * 128;
    const int k0   = blockIdx.z * kChunk;

    const int wm  = (wave >> 1) * 64;   // 2x2 wave grid, 64x64 per wave
    const int wn  = (wave & 1) * 64;
    const int l15 = lane & 15;
    const int g8  = (lane >> 4) * 8;

    f32x4 acc[4][4];
    const f32x4 zero = {0.f, 0.f, 0.f, 0.f};
#pragma unroll
    for (int i = 0; i < 4; i++)
#pragma unroll
        for (int j = 0; j < 4; j++) acc[i][j] = zero;

    const int am = t >> 1;          // A staging: row 0..127
    const int ak = (t & 1) * 16;    //            col half 0/16
    const int bn = t & 127;         // B staging: col 0..127
    const int bk = (t >> 7) * 16;   //            k half 0/16

    const float* aSrc = Ag + (size_t)(tM + am) * K + ak;
    const float* bSrc = Bg + (size_t)bk * N + tN + bn;

    for (int kb = k0; kb < k0 + kChunk; kb += 32) {
        { // ---- stage A tile (128x32), row-major in LDS ----
            const float* src = aSrc + kb;
            float v[16];
#pragma unroll
            for (int q = 0; q < 4; q++) {
                const float4 f = *(const float4*)(src + 4 * q);
                v[4*q] = f.x; v[4*q+1] = f.y; v[4*q+2] = f.z; v[4*q+3] = f.w;
            }
            short h[16];
#pragma unroll
            for (int q = 0; q < 16; q++) h[q] = f2bf(v[q]);
            *(bf16x8*)&Ah[am * KPAD + ak]     = *(bf16x8*)&h[0];
            *(bf16x8*)&Ah[am * KPAD + ak + 8] = *(bf16x8*)&h[8];
            if (MODE == 2) {
                short l[16];
#pragma unroll
                for (int q = 0; q < 16; q++) l[q] = f2bf(v[q] - bf2f(h[q]));
                *(bf16x8*)&Al[am * KPAD + ak]     = *(bf16x8*)&l[0];
                *(bf16x8*)&Al[am * KPAD + ak + 8] = *(bf16x8*)&l[8];
            }
        }
        { // ---- stage B tile (32x128), transposed to [n][k] in LDS ----
            const float* src = bSrc + (size_t)kb * N;
            float v[16];
#pragma unroll
            for (int q = 0; q < 16; q++) v[q] = src[(size_t)q * N];
            short h[16];
#pragma unroll
            for (int q = 0; q < 16; q++) h[q] = f2bf(v[q]);
            *(bf16x8*)&Bh[bn * KPAD + bk]     = *(bf16x8*)&h[0];
            *(bf16x8*)&Bh[bn * KPAD + bk + 8] = *(bf16x8*)&h[8];
            if (MODE >= 1) {
                short l[16];
#pragma unroll
                for (int q = 0; q < 16; q++) l[q] = f2bf(v[q] - bf2f(h[q]));
                *(bf16x8*)&Bl[bn * KPAD + bk]     = *(bf16x8*)&l[0];
                *(bf16x8*)&Bl[bn * KPAD + bk + 8] = *(bf16x8*)&l[8];
            }
        }
        __syncthreads();

        bf16x8 aF[4], bF[4], aL2[4], bL2[4];
#pragma unroll
        for (int i = 0; i < 4; i++)
            aF[i] = *(const bf16x8*)&Ah[(wm + i * 16 + l15) * KPAD + g8];
#pragma unroll
        for (int j = 0; j < 4; j++)
            bF[j] = *(const bf16x8*)&Bh[(wn + j * 16 + l15) * KPAD + g8];
        if (MODE == 2)
#pragma unroll
            for (int i = 0; i < 4; i++)
                aL2[i] = *(const bf16x8*)&Al[(wm + i * 16 + l15) * KPAD + g8];
        if (MODE >= 1)
#pragma unroll
            for (int j = 0; j < 4; j++)
                bL2[j] = *(const bf16x8*)&Bl[(wn + j * 16 + l15) * KPAD + g8];

#pragma unroll
        for (int i = 0; i < 4; i++)
#pragma unroll
            for (int j = 0; j < 4; j++) {
                acc[i][j] = __builtin_amdgcn_mfma_f32_16x16x32_bf16(aF[i], bF[j], acc[i][j], 0, 0, 0);
                if (MODE >= 1)
                    acc[i][j] = __builtin_amdgcn_mfma_f32_16x16x32_bf16(aF[i], bL2[j], acc[i][j], 0, 0, 0);
                if (MODE == 2)
                    acc[i][j] = __builtin_amdgcn_mfma_f32_16x16x32_bf16(aL2[i], bF[j], acc[i][j], 0, 0, 0);
            }
        __syncthreads();
    }

    // epilogue: C/D layout col=lane&15, row=(lane>>4)*4+reg  [m89-verified]
    const int r4 = (lane >> 4) * 4;
#pragma unroll
    for (int i = 0; i < 4; i++)
#pragma unroll
        for (int j = 0; j < 4; j++) {
            const int col = tN + wn + j * 16 + l15;
            float* cp = Cg + (size_t)(tM + wm + i * 16 + r4) * N + col;
#pragma unroll
            for (int r = 0; r < 4; r++) {
                if (SPLITK) atomicAdd(cp + (size_t)r * N, acc[i][j][r]);
                else        cp[(size_t)r * N] = acc[i][j][r];
            }
        }
}

// ---------------------------------------------------------------------------
// Utility kernels
// ---------------------------------------------------------------------------

__global__ void build_adj_kernel(const int* __restrict__ ei, int E,
                                 float* __restrict__ A, int n)
{
    int e = blockIdx.x * 256 + threadIdx.x;
    if (e >= E) return;
    int i = ei[e], j = ei[E + e];
    if (i != j) {
        A[(size_t)i * n + j] = 1.f;
        A[(size_t)j * n + i] = 1.f;
    }
}

// dinv[i] = 1/sqrt(rowsum(A)+2)  (improved GCN: Ah = A + 2I, diag(A)=0)
__global__ void rowsum_dinv_kernel(const float* __restrict__ A, int n,
                                   float* __restrict__ dinv)
{
    int row = blockIdx.x * (blockDim.x >> 6) + (threadIdx.x >> 6);
    if (row >= n) return;
    int lane = threadIdx.x & 63;
    const float* ar = A + (size_t)row * n;
    float s = 0.f;
    for (int c = lane; c < n; c += 64) s += ar[c];
    for (int off = 32; off; off >>= 1) s += __shfl_down(s, off);
    if (lane == 0) dinv[row] = 1.f / sqrtf(s + 2.f);
}

__global__ void scale_rows_kernel(const float* __restrict__ xw,
                                  const float* __restrict__ dinv,
                                  float* __restrict__ z, int total, int C)
{
    int t = blockIdx.x * 256 + threadIdx.x;
    if (t >= total) return;
    z[t] = xw[t] * dinv[t / C];
}

__global__ void gcn_final_kernel(const float* __restrict__ az,
                                 const float* __restrict__ xw,
                                 const float* __restrict__ dinv,
                                 const float* __restrict__ b,
                                 float* __restrict__ out,
                                 int total, int C, int relu)
{
    int t = blockIdx.x * 256 + threadIdx.x;
    if (t >= total) return;
    int i = t / C, c = t - i * C;
    float d = dinv[i];
    float v = d * az[t] + 2.f * d * d * xw[t] + b[c];
    out[t] = (relu && v < 0.f) ? 0.f : v;
}

// Caug = A@A (in Caug) + 2A, diag forced to 0
__global__ void aug_finish_kernel(float* __restrict__ Caug,
                                  const float* __restrict__ A, int n)
{
    size_t t = (size_t)blockIdx.x * 256 + threadIdx.x;
    if (t >= (size_t)n * n) return;
    int i = (int)(t / n), j = (int)(t - (size_t)i * n);
    Caug[t] = (i == j) ? 0.f : (Caug[t] + 2.f * A[t]);
}

__global__ void norm_kernel(const float* __restrict__ p, int C, double* out)
{
    int lane = threadIdx.x & 63;
    double acc = 0.0;
    for (int c = lane; c < C; c += 64) acc += (double)p[c] * (double)p[c];
    for (int off = 32; off; off >>= 1) acc += __shfl_down(acc, off);
    if (lane == 0) *out = sqrt(acc);
}

__global__ void score_kernel(const float* __restrict__ x,
                             const float* __restrict__ p,
                             const double* __restrict__ nrm,
                             float* __restrict__ score, int n, int C)
{
    int row = blockIdx.x * (blockDim.x >> 6) + (threadIdx.x >> 6);
    if (row >= n) return;
    int lane = threadIdx.x & 63;
    const float* xr = x + (size_t)row * C;
    double acc = 0.0;
    for (int c = lane; c < C; c += 64) acc += (double)xr[c] * (double)p[c];
    for (int off = 32; off; off >>= 1) acc += __shfl_down(acc, off);
    if (lane == 0) score[row] = tanhf((float)(acc / (*nrm)));
}

// single-block bitonic sort, (score desc, idx asc) — matches jax.lax.top_k
__global__ __launch_bounds__(1024)
void sort_kernel(const float* __restrict__ score, int n,
                 int* __restrict__ perm, float* __restrict__ vals, int k)
{
    __shared__ float s[4096];
    __shared__ int  idx[4096];
    for (int i = threadIdx.x; i < n; i += blockDim.x) { s[i] = score[i]; idx[i] = i; }
    __syncthreads();
    for (int kk = 2; kk <= n; kk <<= 1) {
        for (int j = kk >> 1; j > 0; j >>= 1) {
            for (int i = threadIdx.x; i < n; i += blockDim.x) {
                int ixj = i ^ j;
                if (ixj > i) {
                    float si = s[i], sx = s[ixj];
                    int   ii = idx[i], ix = idx[ixj];
                    bool aBefore = (si > sx) || (si == sx && ii < ix);
                    bool dirDesc = ((i & kk) == 0);
                    if (aBefore != dirDesc) {
                        s[i] = sx; s[ixj] = si; idx[i] = ix; idx[ixj] = ii;
                    }
                }
            }
            __syncthreads();
        }
    }
    for (int r = threadIdx.x; r < k; r += blockDim.x) { perm[r] = idx[r]; vals[r] = s[r]; }
}

__global__ void gather_x_kernel(const float* __restrict__ xold,
                                const int* __restrict__ perm,
                                const float* __restrict__ vals,
                                float* __restrict__ xnew, int total, int C)
{
    int t = blockIdx.x * 256 + threadIdx.x;
    if (t >= total) return;
    int r = t / C, c = t - r * C;
    xnew[t] = xold[(size_t)perm[r] * C + c] * vals[r];
}

__global__ void gather_A_kernel(const float* __restrict__ Aaug, int n,
                                const int* __restrict__ perm,
                                float* __restrict__ Anew, int kn)
{
    int t = blockIdx.x * 256 + threadIdx.x;
    if (t >= kn * kn) return;
    int r = t / kn, c = t - r * kn;
    Anew[t] = Aaug[(size_t)perm[r] * n + perm[c]];
}

__global__ void scatter_add_kernel(float* __restrict__ dst,
                                   const float* __restrict__ src,
                                   const int* __restrict__ perm,
                                   int total, int C)
{
    int t = blockIdx.x * 256 + threadIdx.x;
    if (t >= total) return;
    int r = t / C, c = t - r * C;
    dst[(size_t)perm[r] * C + c] += src[t];
}

// ---------------------------------------------------------------------------
// Host orchestration
// ---------------------------------------------------------------------------

extern "C" void kernel_launch(void* const* d_in, const int* in_sizes, int n_in,
                              void* d_out, int out_size, void* d_ws, size_t ws_size,
                              hipStream_t stream)
{
    const float* x0  = (const float*)d_in[0];
    const int*   ei  = (const int*)d_in[1];
    const float* Wd0 = (const float*)d_in[2];  const float* bd0 = (const float*)d_in[3];
    const float* Wd1 = (const float*)d_in[4];  const float* bd1 = (const float*)d_in[5];
    const float* Wd2 = (const float*)d_in[6];  const float* bd2 = (const float*)d_in[7];
    const float* Wd3 = (const float*)d_in[8];  const float* bd3 = (const float*)d_in[9];
    const float* p1  = (const float*)d_in[10];
    const float* p2  = (const float*)d_in[11];
    const float* p3  = (const float*)d_in[12];
    const float* Wu0 = (const float*)d_in[13]; const float* bu0 = (const float*)d_in[14];
    const float* Wu1 = (const float*)d_in[15]; const float* bu1 = (const float*)d_in[16];
    const float* Wu2 = (const float*)d_in[17]; const float* bu2 = (const float*)d_in[18];

    const int E = in_sizes[1] / 2;
    const int N0 = 4096, HID = 256;

    char* ws = (char*)d_ws;
    size_t off = 0;
    auto alloc = [&](size_t bytes) -> void* {
        void* p = ws + off;
        off += (bytes + 255) & ~(size_t)255;
        return p;
    };
    float* A0f   = (float*)alloc((size_t)4096 * 4096 * 4);
    float* Cf    = (float*)alloc((size_t)4096 * 4096 * 4);
    float* As1f  = (float*)alloc((size_t)2048 * 2048 * 4);
    float* As2f  = (float*)alloc((size_t)1024 * 1024 * 4);
    float* A3f   = (float*)alloc((size_t)512 * 512 * 4);
    float* xs0   = (float*)alloc((size_t)4096 * 256 * 4);
    float* xs1   = (float*)alloc((size_t)2048 * 256 * 4);
    float* xs2   = (float*)alloc((size_t)1024 * 256 * 4);
    float* xwb   = (float*)alloc((size_t)4096 * 256 * 4);
    float* zzb   = (float*)alloc((size_t)4096 * 256 * 4);
    float* azb   = (float*)alloc((size_t)4096 * 256 * 4);
    float* xa    = (float*)alloc((size_t)2048 * 256 * 4);
    float* xb    = (float*)alloc((size_t)2048 * 256 * 4);
    float* xu    = (float*)alloc((size_t)4096 * 256 * 4);
    float* dinvb = (float*)alloc(4096 * 4);
    float* scoreb= (float*)alloc(4096 * 4);
    float* valsb = (float*)alloc(2048 * 4);
    int*   perm1 = (int*)alloc(2048 * 4);
    int*   perm2 = (int*)alloc(1024 * 4);
    int*   perm3 = (int*)alloc(512 * 4);
    double* nrm  = (double*)alloc(256);

    auto gemm = [&](int mode, const float* A, const float* B, float* C,
                    int M, int Nn, int K) {
        int Mb = M / 128, Nb = Nn / 128;
        int S = 1;
        if (Mb * Nb < 256 && K >= 1024) { S = K / 512; if (S > 8) S = 8; }
        int kChunk = K / S;
        dim3 g(Nb, Mb, S);
        if (S > 1) {
            hipMemsetAsync(C, 0, (size_t)M * Nn * 4, stream);
            switch (mode) {
            case 0: gemm_tile<0, true><<<g, 256, 0, stream>>>(A, B, C, M, Nn, K, kChunk); break;
            case 1: gemm_tile<1, true><<<g, 256, 0, stream>>>(A, B, C, M, Nn, K, kChunk); break;
            default: gemm_tile<2, true><<<g, 256, 0, stream>>>(A, B, C, M, Nn, K, kChunk); break;
            }
        } else {
            switch (mode) {
            case 0: gemm_tile<0, false><<<g, 256, 0, stream>>>(A, B, C, M, Nn, K, kChunk); break;
            case 1: gemm_tile<1, false><<<g, 256, 0, stream>>>(A, B, C, M, Nn, K, kChunk); break;
            default: gemm_tile<2, false><<<g, 256, 0, stream>>>(A, B, C, M, Nn, K, kChunk); break;
            }
        }
    };

    // GCN: out = relu?( dinv*(A @ (dinv*xW)) + 2*dinv^2*(xW) + b )
    auto gcn = [&](const float* xinp, int n, int Kc, int Cout, const float* A,
                   const float* W, const float* b, float* out, bool relu, int modeA) {
        gemm(2, xinp, W, xwb, n, Cout, Kc);
        rowsum_dinv_kernel<<<n / 4, 256, 0, stream>>>(A, n, dinvb);
        int tot = n * Cout;
        scale_rows_kernel<<<tot / 256, 256, 0, stream>>>(xwb, dinvb, zzb, tot, Cout);
        gemm(modeA, A, zzb, azb, n, Cout, n);
        gcn_final_kernel<<<tot / 256, 256, 0, stream>>>(azb, xwb, dinvb, b, out, tot, Cout, (int)relu);
    };

    auto pool = [&](const float* xlev, const float* Aaug, int n, const float* p,
                    int* perm, float* xout, float* Aout) {
        int k = n / 2;
        norm_kernel<<<1, 64, 0, stream>>>(p, HID, nrm);
        score_kernel<<<n / 4, 256, 0, stream>>>(xlev, p, nrm, scoreb, n, HID);
        sort_kernel<<<1, 1024, 0, stream>>>(scoreb, n, perm, valsb, k);
        gather_x_kernel<<<(k * HID) / 256, 256, 0, stream>>>(xlev, perm, valsb, xout, k * HID, HID);
        gather_A_kernel<<<(k * k + 255) / 256, 256, 0, stream>>>(Aaug, n, perm, Aout, k);
    };

    // ---- build adjacency ----
    hipMemsetAsync(A0f, 0, (size_t)4096 * 4096 * 4, stream);
    build_adj_kernel<<<(E + 255) / 256, 256, 0, stream>>>(ei, E, A0f, N0);

    // ---- down: level-0 GCN ----
    gcn(x0, 4096, 128, 256, A0f, Wd0, bd0, xs0, true, 1);

    // ---- level 0 -> 1 ----
    gemm(0, A0f, A0f, Cf, 4096, 4096, 4096);                 // A0 in {0,1}: bf16 exact
    aug_finish_kernel<<<(4096 * 4096) / 256, 256, 0, stream>>>(Cf, A0f, 4096);
    pool(xs0, Cf, 4096, p1, perm1, xa, As1f);
    gcn(xa, 2048, 256, 256, As1f, Wd1, bd1, xs1, true, 1);   // A1 ints<=256: exact

    // ---- level 1 -> 2 ----
    gemm(0, As1f, As1f, Cf, 2048, 2048, 2048);               // small ints: bf16 exact
    aug_finish_kernel<<<(2048 * 2048) / 256, 256, 0, stream>>>(Cf, As1f, 2048);
    pool(xs1, Cf, 2048, p2, perm2, xa, As2f);
    gcn(xa, 1024, 256, 256, As2f, Wd2, bd2, xs2, true, 2);   // A2 ints<2^16: hi/lo

    // ---- level 2 -> 3 ----
    gemm(2, As2f, As2f, Cf, 1024, 1024, 1024);
    aug_finish_kernel<<<(1024 * 1024) / 256, 256, 0, stream>>>(Cf, As2f, 1024);
    pool(xs2, Cf, 1024, p3, perm3, xa, A3f);
    gcn(xa, 512, 256, 256, A3f, Wd3, bd3, xb, true, 2);

    // ---- up 0 (j=2) ----
    hipMemcpyAsync(xu, xs2, (size_t)1024 * 256 * 4, hipMemcpyDeviceToDevice, stream);
    scatter_add_kernel<<<(512 * 256) / 256, 256, 0, stream>>>(xu, xb, perm3, 512 * 256, 256);
    gcn(xu, 1024, 256, 256, As2f, Wu0, bu0, xa, true, 2);

    // ---- up 1 (j=1) ----
    hipMemcpyAsync(xu, xs1, (size_t)2048 * 256 * 4, hipMemcpyDeviceToDevice, stream);
    scatter_add_kernel<<<(1024 * 256) / 256, 256, 0, stream>>>(xu, xa, perm2, 1024 * 256, 256);
    gcn(xu, 2048, 256, 256, As1f, Wu1, bu1, xb, true, 1);

    // ---- up 2 (j=0), final: no relu, Cout=128, straight to d_out ----
    hipMemcpyAsync(xu, xs0, (size_t)4096 * 256 * 4, hipMemcpyDeviceToDevice, stream);
    scatter_add_kernel<<<(2048 * 256) / 256, 256, 0, stream>>>(xu, xb, perm1, 2048 * 256, 256);
    gcn(xu, 4096, 256, 128, A0f, Wu2, bu2, (float*)d_out, false, 1);
}

// Round 2
// 785.770 us; speedup vs baseline: 1.6021x; 1.6021x over previous
//
#include <hip/hip_runtime.h>

// ---------------------------------------------------------------------------
// GraphUNet on MI355X.  N=4096, IN_C=128, HID=256, OUT_C=128, DEPTH=3,
// KS={2048,1024,512}.
//
// Round-2 structure:
//  * augment+pool fused: A_{i+1} = (G @ G^T) with G=(A_i+I)[perm,:], diag=0
//    (perm depends only on x-scores, A symmetric) -> 4x fewer FLOPs.
//  * all heavy GEMMs in bf16 BT-layout kernel with global_load_lds width=16
//    (m97 structure), operands pre-split hi/lo for exactness.
// ---------------------------------------------------------------------------

typedef __attribute__((ext_vector_type(8))) short bf16x8;
typedef __attribute__((ext_vector_type(4))) float f32x4;

__device__ __forceinline__ short f2bf(float f) {
    unsigned u = __builtin_bit_cast(unsigned, f);
    u += 0x7FFFu + ((u >> 16) & 1u);          // RNE
    return (short)(u >> 16);
}
__device__ __forceinline__ float bf2f(short s) {
    unsigned u = ((unsigned)(unsigned short)s) << 16;
    return __builtin_bit_cast(float, u);
}

#define GLL16(gsrc, ldst)                                                        \
    __builtin_amdgcn_global_load_lds(                                            \
        (__attribute__((address_space(1))) void*)(gsrc),                         \
        (__attribute__((address_space(3))) void*)(ldst), 16, 0, 0)

// ---------------------------------------------------------------------------
// bf16 BT GEMM: C(MxN) = A(MxK) @ B^T  where B is stored N x K row-major.
// MODE 0: Ah@Bh            (exact for small-int inputs)
// MODE 1: Ah@(Bh+Bl)       (A exact, B real-valued)
// MODE 2: Ah@Bh + Ah@Bl + Al@Bh   (both split; drops lo*lo ~2^-18 rel)
// SPLITK: grid.z chunks over K, fp32 atomicAdd into pre-zeroed C.
// All of M,N multiples of 128; K,kChunk multiples of 32.
// ---------------------------------------------------------------------------
template<int MODE, bool SPLITK>
__global__ __launch_bounds__(256, 2)
void gemm_bt(const short* __restrict__ Ah, const short* __restrict__ Al,
             const short* __restrict__ Bh, const short* __restrict__ Bl,
             float* __restrict__ Cg, int M, int N, int K, int kChunk)
{
    __shared__ short sAh[128 * 32];
    __shared__ short sBh[128 * 32];
    __shared__ short sAl[(MODE == 2) ? 128 * 32 : 8];
    __shared__ short sBl[(MODE >= 1) ? 128 * 32 : 8];

    const int t    = threadIdx.x;
    const int lane = t & 63;
    const int wave = t >> 6;
    const int tM   = blockIdx.y * 128;
    const int tN   = blockIdx.x * 128;
    const int k0   = blockIdx.z * kChunk;

    const int wm  = (wave >> 1) * 64;
    const int wn  = (wave & 1) * 64;
    const int l15 = lane & 15;
    const int g8  = (lane >> 4) * 8;

    f32x4 acc[4][4];
    const f32x4 zero = {0.f, 0.f, 0.f, 0.f};
#pragma unroll
    for (int i = 0; i < 4; i++)
#pragma unroll
        for (int j = 0; j < 4; j++) acc[i][j] = zero;

    // staging: 128x32 bf16 tile = 8 KB = 256 thr x 2 issues x 16 B.
    // chunk idx -> row = idx>>2, k-offset = (idx&3)*8. LDS dst = idx*16 B
    // (wave-uniform base + lane*16 — required by global_load_lds).
    const int i0 = t, i1 = t + 256;
    const short* a0 = Ah + (size_t)(tM + (i0 >> 2)) * K + (i0 & 3) * 8;
    const short* a1 = Ah + (size_t)(tM + (i1 >> 2)) * K + (i1 & 3) * 8;
    const short* b0 = Bh + (size_t)(tN + (i0 >> 2)) * K + (i0 & 3) * 8;
    const short* b1 = Bh + (size_t)(tN + (i1 >> 2)) * K + (i1 & 3) * 8;
    const short *bl0 = nullptr, *bl1 = nullptr, *al0 = nullptr, *al1 = nullptr;
    if (MODE >= 1) {
        bl0 = Bl + (size_t)(tN + (i0 >> 2)) * K + (i0 & 3) * 8;
        bl1 = Bl + (size_t)(tN + (i1 >> 2)) * K + (i1 & 3) * 8;
    }
    if (MODE == 2) {
        al0 = Al + (size_t)(tM + (i0 >> 2)) * K + (i0 & 3) * 8;
        al1 = Al + (size_t)(tM + (i1 >> 2)) * K + (i1 & 3) * 8;
    }

    for (int kb = k0; kb < k0 + kChunk; kb += 32) {
        GLL16(a0 + kb, &sAh[i0 * 8]);
        GLL16(a1 + kb, &sAh[i1 * 8]);
        GLL16(b0 + kb, &sBh[i0 * 8]);
        GLL16(b1 + kb, &sBh[i1 * 8]);
        if (MODE >= 1) { GLL16(bl0 + kb, &sBl[i0 * 8]); GLL16(bl1 + kb, &sBl[i1 * 8]); }
        if (MODE == 2) { GLL16(al0 + kb, &sAl[i0 * 8]); GLL16(al1 + kb, &sAl[i1 * 8]); }
        __syncthreads();   // drains vmcnt -> LDS visible

        bf16x8 aF[4], bF[4], aL[4], bL[4];
#pragma unroll
        for (int i = 0; i < 4; i++)
            aF[i] = *(const bf16x8*)&sAh[(wm + i * 16 + l15) * 32 + g8];
#pragma unroll
        for (int j = 0; j < 4; j++)
            bF[j] = *(const bf16x8*)&sBh[(wn + j * 16 + l15) * 32 + g8];
        if (MODE >= 1)
#pragma unroll
            for (int j = 0; j < 4; j++)
                bL[j] = *(const bf16x8*)&sBl[(wn + j * 16 + l15) * 32 + g8];
        if (MODE == 2)
#pragma unroll
            for (int i = 0; i < 4; i++)
                aL[i] = *(const bf16x8*)&sAl[(wm + i * 16 + l15) * 32 + g8];

#pragma unroll
        for (int i = 0; i < 4; i++)
#pragma unroll
            for (int j = 0; j < 4; j++) {
                acc[i][j] = __builtin_amdgcn_mfma_f32_16x16x32_bf16(aF[i], bF[j], acc[i][j], 0, 0, 0);
                if (MODE >= 1)
                    acc[i][j] = __builtin_amdgcn_mfma_f32_16x16x32_bf16(aF[i], bL[j], acc[i][j], 0, 0, 0);
                if (MODE == 2)
                    acc[i][j] = __builtin_amdgcn_mfma_f32_16x16x32_bf16(aL[i], bF[j], acc[i][j], 0, 0, 0);
            }
        __syncthreads();
    }

    // C/D layout: col=lane&15, row=(lane>>4)*4+reg  [m89-verified]
    const int r4 = (lane >> 4) * 4;
#pragma unroll
    for (int i = 0; i < 4; i++)
#pragma unroll
        for (int j = 0; j < 4; j++) {
            const int col = tN + wn + j * 16 + l15;
            float* cp = Cg + (size_t)(tM + wm + i * 16 + r4) * N + col;
#pragma unroll
            for (int r = 0; r < 4; r++) {
                if (SPLITK) atomicAdd(cp + (size_t)r * N, acc[i][j][r]);
                else        cp[(size_t)r * N] = acc[i][j][r];
            }
        }
}

// ---------------------------------------------------------------------------
// fp32-input GEMM (round-1 kernel) — used only for tiny x@W products.
// C = A(MxK) @ B(KxN), hi/lo 3-pass inside.
// ---------------------------------------------------------------------------
#define KPAD 40
__global__ __launch_bounds__(256, 2)
void gemm_f32_tile(const float* __restrict__ Ag, const float* __restrict__ Bg,
                   float* __restrict__ Cg, int M, int N, int K)
{
    __shared__ short Ah[128 * KPAD];
    __shared__ short Bh[128 * KPAD];
    __shared__ short Al[128 * KPAD];
    __shared__ short Bl[128 * KPAD];

    const int t    = threadIdx.x;
    const int lane = t & 63;
    const int wave = t >> 6;
    const int tM   = blockIdx.y * 128;
    const int tN   = blockIdx.x * 128;

    const int wm  = (wave >> 1) * 64;
    const int wn  = (wave & 1) * 64;
    const int l15 = lane & 15;
    const int g8  = (lane >> 4) * 8;

    f32x4 acc[4][4];
    const f32x4 zero = {0.f, 0.f, 0.f, 0.f};
#pragma unroll
    for (int i = 0; i < 4; i++)
#pragma unroll
        for (int j = 0; j < 4; j++) acc[i][j] = zero;

    const int am = t >> 1;
    const int ak = (t & 1) * 16;
    const int bn = t & 127;
    const int bk = (t >> 7) * 16;

    const float* aSrc = Ag + (size_t)(tM + am) * K + ak;
    const float* bSrc = Bg + (size_t)bk * N + tN + bn;

    for (int kb = 0; kb < K; kb += 32) {
        {
            const float* src = aSrc + kb;
            float v[16];
#pragma unroll
            for (int q = 0; q < 4; q++) {
                const float4 f = *(const float4*)(src + 4 * q);
                v[4*q] = f.x; v[4*q+1] = f.y; v[4*q+2] = f.z; v[4*q+3] = f.w;
            }
            short h[16], l[16];
#pragma unroll
            for (int q = 0; q < 16; q++) { h[q] = f2bf(v[q]); l[q] = f2bf(v[q] - bf2f(h[q])); }
            *(bf16x8*)&Ah[am * KPAD + ak]     = *(bf16x8*)&h[0];
            *(bf16x8*)&Ah[am * KPAD + ak + 8] = *(bf16x8*)&h[8];
            *(bf16x8*)&Al[am * KPAD + ak]     = *(bf16x8*)&l[0];
            *(bf16x8*)&Al[am * KPAD + ak + 8] = *(bf16x8*)&l[8];
        }
        {
            const float* src = bSrc + (size_t)kb * N;
            float v[16];
#pragma unroll
            for (int q = 0; q < 16; q++) v[q] = src[(size_t)q * N];
            short h[16], l[16];
#pragma unroll
            for (int q = 0; q < 16; q++) { h[q] = f2bf(v[q]); l[q] = f2bf(v[q] - bf2f(h[q])); }
            *(bf16x8*)&Bh[bn * KPAD + bk]     = *(bf16x8*)&h[0];
            *(bf16x8*)&Bh[bn * KPAD + bk + 8] = *(bf16x8*)&h[8];
            *(bf16x8*)&Bl[bn * KPAD + bk]     = *(bf16x8*)&l[0];
            *(bf16x8*)&Bl[bn * KPAD + bk + 8] = *(bf16x8*)&l[8];
        }
        __syncthreads();

        bf16x8 aF[4], bF[4], aL2[4], bL2[4];
#pragma unroll
        for (int i = 0; i < 4; i++) {
            aF[i]  = *(const bf16x8*)&Ah[(wm + i * 16 + l15) * KPAD + g8];
            aL2[i] = *(const bf16x8*)&Al[(wm + i * 16 + l15) * KPAD + g8];
        }
#pragma unroll
        for (int j = 0; j < 4; j++) {
            bF[j]  = *(const bf16x8*)&Bh[(wn + j * 16 + l15) * KPAD + g8];
            bL2[j] = *(const bf16x8*)&Bl[(wn + j * 16 + l15) * KPAD + g8];
        }

#pragma unroll
        for (int i = 0; i < 4; i++)
#pragma unroll
            for (int j = 0; j < 4; j++) {
                acc[i][j] = __builtin_amdgcn_mfma_f32_16x16x32_bf16(aF[i],  bF[j],  acc[i][j], 0, 0, 0);
                acc[i][j] = __builtin_amdgcn_mfma_f32_16x16x32_bf16(aF[i],  bL2[j], acc[i][j], 0, 0, 0);
                acc[i][j] = __builtin_amdgcn_mfma_f32_16x16x32_bf16(aL2[i], bF[j],  acc[i][j], 0, 0, 0);
            }
        __syncthreads();
    }

    const int r4 = (lane >> 4) * 4;
#pragma unroll
    for (int i = 0; i < 4; i++)
#pragma unroll
        for (int j = 0; j < 4; j++) {
            const int col = tN + wn + j * 16 + l15;
            float* cp = Cg + (size_t)(tM + wm + i * 16 + r4) * N + col;
#pragma unroll
            for (int r = 0; r < 4; r++) cp[(size_t)r * N] = acc[i][j][r];
        }
}

// ---------------------------------------------------------------------------
// Utility kernels
// ---------------------------------------------------------------------------

__global__ void build_adj_bf16(const int* __restrict__ ei, int E,
                               short* __restrict__ A, int n)
{
    int e = blockIdx.x * 256 + threadIdx.x;
    if (e >= E) return;
    int i = ei[e], j = ei[E + e];
    if (i != j) {
        A[(size_t)i * n + j] = (short)0x3F80;   // bf16 1.0
        A[(size_t)j * n + i] = (short)0x3F80;
    }
}

__global__ void rowsum_dinv_f32(const float* __restrict__ A, int n,
                                float* __restrict__ dinv)
{
    int row = blockIdx.x * (blockDim.x >> 6) + (threadIdx.x >> 6);
    if (row >= n) return;
    int lane = threadIdx.x & 63;
    const float* ar = A + (size_t)row * n;
    float s = 0.f;
    for (int c = lane; c < n; c += 64) s += ar[c];
    for (int off = 32; off; off >>= 1) s += __shfl_down(s, off);
    if (lane == 0) dinv[row] = 1.f / sqrtf(s + 2.f);
}

__global__ void rowsum_dinv_bf16(const short* __restrict__ A, int n,
                                 float* __restrict__ dinv)
{
    int row = blockIdx.x * (blockDim.x >> 6) + (threadIdx.x >> 6);
    if (row >= n) return;
    int lane = threadIdx.x & 63;
    const ushort4* ar = (const ushort4*)(A + (size_t)row * n);
    float s = 0.f;
    for (int c = lane; c < (n >> 2); c += 64) {
        ushort4 u = ar[c];
        s += bf2f((short)u.x) + bf2f((short)u.y) + bf2f((short)u.z) + bf2f((short)u.w);
    }
    for (int off = 32; off; off >>= 1) s += __shfl_down(s, off);
    if (lane == 0) dinv[row] = 1.f / sqrtf(s + 2.f);
}

// Z^T hi/lo: Zt[c*n + r] = split( xw[r*C + c] * dinv[r] )
__global__ void sts_kernel(const float* __restrict__ xw,
                           const float* __restrict__ dinv,
                           short* __restrict__ Zh, short* __restrict__ Zl,
                           int n, int C)
{
    int t = blockIdx.x * 256 + threadIdx.x;
    if (t >= n * C) return;
    int c = t / n, r = t - c * n;
    float v = xw[(size_t)r * C + c] * dinv[r];
    short h = f2bf(v);
    Zh[t] = h;
    Zl[t] = f2bf(v - bf2f(h));
}

__global__ void gcn_final_kernel(const float* __restrict__ az,
                                 const float* __restrict__ xw,
                                 const float* __restrict__ dinv,
                                 const float* __restrict__ b,
                                 float* __restrict__ out,
                                 int total, int C, int relu)
{
    int t = blockIdx.x * 256 + threadIdx.x;
    if (t >= total) return;
    int i = t / C, c = t - i * C;
    float d = dinv[i];
    float v = d * az[t] + 2.f * d * d * xw[t] + b[c];
    out[t] = (relu && v < 0.f) ? 0.f : v;
}

// G = (A+I)[perm,:] in bf16 hi (A itself bf16-exact)
__global__ void gatherG_bf16(const short* __restrict__ A, int n,
                             const int* __restrict__ perm,
                             short* __restrict__ Gh, int k)
{
    int t = blockIdx.x * 256 + threadIdx.x;
    if (t >= k * n) return;
    int r = t / n, c = t - r * n;
    int pr = perm[r];
    float v = bf2f(A[(size_t)pr * n + c]) + (c == pr ? 1.f : 0.f);
    Gh[t] = f2bf(v);
}

// G = (A+I)[perm,:] hi(/lo) from fp32 A
__global__ void gatherG_f32(const float* __restrict__ A, int n,
                            const int* __restrict__ perm,
                            short* __restrict__ Gh, short* __restrict__ Gl, int k)
{
    int t = blockIdx.x * 256 + threadIdx.x;
    if (t >= k * n) return;
    int r = t / n, c = t - r * n;
    int pr = perm[r];
    float v = A[(size_t)pr * n + c] + (c == pr ? 1.f : 0.f);
    short h = f2bf(v);
    Gh[t] = h;
    if (Gl) Gl[t] = f2bf(v - bf2f(h));
}

// A_next = Cf with diag zeroed; also emit bf16 hi(/lo)
__global__ void aug_finish2(const float* __restrict__ Cf,
                            float* __restrict__ Af,
                            short* __restrict__ Ahs, short* __restrict__ Als, int k)
{
    int t = blockIdx.x * 256 + threadIdx.x;
    if (t >= k * k) return;
    int r = t / k, c = t - r * k;
    float v = (r == c) ? 0.f : Cf[t];
    Af[t] = v;
    short h = f2bf(v);
    Ahs[t] = h;
    if (Als) Als[t] = f2bf(v - bf2f(h));
}

__global__ void norm_kernel(const float* __restrict__ p, int C, double* out)
{
    int lane = threadIdx.x & 63;
    double acc = 0.0;
    for (int c = lane; c < C; c += 64) acc += (double)p[c] * (double)p[c];
    for (int off = 32; off; off >>= 1) acc += __shfl_down(acc, off);
    if (lane == 0) *out = sqrt(acc);
}

__global__ void score_kernel(const float* __restrict__ x,
                             const float* __restrict__ p,
                             const double* __restrict__ nrm,
                             float* __restrict__ score, int n, int C)
{
    int row = blockIdx.x * (blockDim.x >> 6) + (threadIdx.x >> 6);
    if (row >= n) return;
    int lane = threadIdx.x & 63;
    const float* xr = x + (size_t)row * C;
    double acc = 0.0;
    for (int c = lane; c < C; c += 64) acc += (double)xr[c] * (double)p[c];
    for (int off = 32; off; off >>= 1) acc += __shfl_down(acc, off);
    if (lane == 0) score[row] = tanhf((float)(acc / (*nrm)));
}

// single-block bitonic sort, (score desc, idx asc) — matches jax.lax.top_k
__global__ __launch_bounds__(1024)
void sort_kernel(const float* __restrict__ score, int n,
                 int* __restrict__ perm, float* __restrict__ vals, int k)
{
    __shared__ float s[4096];
    __shared__ int  idx[4096];
    for (int i = threadIdx.x; i < n; i += blockDim.x) { s[i] = score[i]; idx[i] = i; }
    __syncthreads();
    for (int kk = 2; kk <= n; kk <<= 1) {
        for (int j = kk >> 1; j > 0; j >>= 1) {
            for (int i = threadIdx.x; i < n; i += blockDim.x) {
                int ixj = i ^ j;
                if (ixj > i) {
                    float si = s[i], sx = s[ixj];
                    int   ii = idx[i], ix = idx[ixj];
                    bool aBefore = (si > sx) || (si == sx && ii < ix);
                    bool dirDesc = ((i & kk) == 0);
                    if (aBefore != dirDesc) {
                        s[i] = sx; s[ixj] = si; idx[i] = ix; idx[ixj] = ii;
                    }
                }
            }
            __syncthreads();
        }
    }
    for (int r = threadIdx.x; r < k; r += blockDim.x) { perm[r] = idx[r]; vals[r] = s[r]; }
}

__global__ void gather_x_kernel(const float* __restrict__ xold,
                                const int* __restrict__ perm,
                                const float* __restrict__ vals,
                                float* __restrict__ xnew, int total, int C)
{
    int t = blockIdx.x * 256 + threadIdx.x;
    if (t >= total) return;
    int r = t / C, c = t - r * C;
    xnew[t] = xold[(size_t)perm[r] * C + c] * vals[r];
}

__global__ void scatter_add_kernel(float* __restrict__ dst,
                                   const float* __restrict__ src,
                                   const int* __restrict__ perm,
                                   int total, int C)
{
    int t = blockIdx.x * 256 + threadIdx.x;
    if (t >= total) return;
    int r = t / C, c = t - r * C;
    dst[(size_t)perm[r] * C + c] += src[t];
}

// ---------------------------------------------------------------------------
// Host orchestration
// ---------------------------------------------------------------------------

extern "C" void kernel_launch(void* const* d_in, const int* in_sizes, int n_in,
                              void* d_out, int out_size, void* d_ws, size_t ws_size,
                              hipStream_t stream)
{
    const float* x0  = (const float*)d_in[0];
    const int*   ei  = (const int*)d_in[1];
    const float* Wd0 = (const float*)d_in[2];  const float* bd0 = (const float*)d_in[3];
    const float* Wd1 = (const float*)d_in[4];  const float* bd1 = (const float*)d_in[5];
    const float* Wd2 = (const float*)d_in[6];  const float* bd2 = (const float*)d_in[7];
    const float* Wd3 = (const float*)d_in[8];  const float* bd3 = (const float*)d_in[9];
    const float* p1  = (const float*)d_in[10];
    const float* p2  = (const float*)d_in[11];
    const float* p3  = (const float*)d_in[12];
    const float* Wu0 = (const float*)d_in[13]; const float* bu0 = (const float*)d_in[14];
    const float* Wu1 = (const float*)d_in[15]; const float* bu1 = (const float*)d_in[16];
    const float* Wu2 = (const float*)d_in[17]; const float* bu2 = (const float*)d_in[18];

    const int E = in_sizes[1] / 2;
    const int HID = 256;

    char* ws = (char*)d_ws;
    size_t off = 0;
    auto alloc = [&](size_t bytes) -> void* {
        void* p = ws + off;
        off += (bytes + 255) & ~(size_t)255;
        return p;
    };
    short* A0h  = (short*)alloc((size_t)4096 * 4096 * 2);
    float* Cf   = (float*)alloc((size_t)2048 * 2048 * 4);
    float* A1f  = (float*)alloc((size_t)2048 * 2048 * 4);
    short* A1h  = (short*)alloc((size_t)2048 * 2048 * 2);
    float* A2f  = (float*)alloc((size_t)1024 * 1024 * 4);
    short* A2h  = (short*)alloc((size_t)1024 * 1024 * 2);
    short* A2l  = (short*)alloc((size_t)1024 * 1024 * 2);
    float* A3f  = (float*)alloc((size_t)512 * 512 * 4);
    short* A3h  = (short*)alloc((size_t)512 * 512 * 2);
    short* A3l  = (short*)alloc((size_t)512 * 512 * 2);
    short* Gh   = (short*)alloc((size_t)2048 * 4096 * 2);
    short* Gl   = (short*)alloc((size_t)512 * 1024 * 2);
    float* xs0  = (float*)alloc((size_t)4096 * 256 * 4);
    float* xs1  = (float*)alloc((size_t)2048 * 256 * 4);
    float* xs2  = (float*)alloc((size_t)1024 * 256 * 4);
    float* xwb  = (float*)alloc((size_t)4096 * 256 * 4);
    float* azb  = (float*)alloc((size_t)4096 * 256 * 4);
    short* Zth  = (short*)alloc((size_t)256 * 4096 * 2);
    short* Ztl  = (short*)alloc((size_t)256 * 4096 * 2);
    float* xa   = (float*)alloc((size_t)2048 * 256 * 4);
    float* xb   = (float*)alloc((size_t)2048 * 256 * 4);
    float* xu   = (float*)alloc((size_t)4096 * 256 * 4);
    float* dinvb  = (float*)alloc(4096 * 4);
    float* scoreb = (float*)alloc(4096 * 4);
    float* valsb  = (float*)alloc(2048 * 4);
    int*   perm1  = (int*)alloc(2048 * 4);
    int*   perm2  = (int*)alloc(1024 * 4);
    int*   perm3  = (int*)alloc(512 * 4);
    double* nrm   = (double*)alloc(256);

    auto gemmBT = [&](int mode, const short* pAh, const short* pAl,
                      const short* pBh, const short* pBl,
                      float* C, int M, int Nn, int K, int S) {
        dim3 g(Nn / 128, M / 128, S);
        int kChunk = K / S;
        if (S > 1) {
            hipMemsetAsync(C, 0, (size_t)M * Nn * 4, stream);
            switch (mode) {
            case 0: gemm_bt<0, true><<<g, 256, 0, stream>>>(pAh, pAl, pBh, pBl, C, M, Nn, K, kChunk); break;
            case 1: gemm_bt<1, true><<<g, 256, 0, stream>>>(pAh, pAl, pBh, pBl, C, M, Nn, K, kChunk); break;
            default: gemm_bt<2, true><<<g, 256, 0, stream>>>(pAh, pAl, pBh, pBl, C, M, Nn, K, kChunk); break;
            }
        } else {
            switch (mode) {
            case 0: gemm_bt<0, false><<<g, 256, 0, stream>>>(pAh, pAl, pBh, pBl, C, M, Nn, K, kChunk); break;
            case 1: gemm_bt<1, false><<<g, 256, 0, stream>>>(pAh, pAl, pBh, pBl, C, M, Nn, K, kChunk); break;
            default: gemm_bt<2, false><<<g, 256, 0, stream>>>(pAh, pAl, pBh, pBl, C, M, Nn, K, kChunk); break;
            }
        }
    };

    // GCN: out = relu?( dinv*(A@(dinv*xW)) + 2*dinv^2*(xW) + b )
    auto gcn = [&](const float* xin, int n, int Kc, int Cout,
                   const float* Afp, const short* pAh, const short* pAl,
                   const float* W, const float* b, float* out, bool relu,
                   int mode, int S) {
        gemm_f32_tile<<<dim3(Cout / 128, n / 128), 256, 0, stream>>>(xin, W, xwb, n, Cout, Kc);
        if (Afp) rowsum_dinv_f32<<<n / 4, 256, 0, stream>>>(Afp, n, dinvb);
        else     rowsum_dinv_bf16<<<n / 4, 256, 0, stream>>>(pAh, n, dinvb);
        sts_kernel<<<(n * Cout) / 256, 256, 0, stream>>>(xwb, dinvb, Zth, Ztl, n, Cout);
        gemmBT(mode, pAh, pAl, Zth, Ztl, azb, n, Cout, n, S);
        gcn_final_kernel<<<(n * Cout) / 256, 256, 0, stream>>>(azb, xwb, dinvb, b, out, n * Cout, Cout, (int)relu);
    };

    auto pool = [&](const float* xlev, int n, const float* p, int* perm, float* xout) {
        int k = n / 2;
        norm_kernel<<<1, 64, 0, stream>>>(p, HID, nrm);
        score_kernel<<<n / 4, 256, 0, stream>>>(xlev, p, nrm, scoreb, n, HID);
        sort_kernel<<<1, 1024, 0, stream>>>(scoreb, n, perm, valsb, k);
        gather_x_kernel<<<(k * HID) / 256, 256, 0, stream>>>(xlev, perm, valsb, xout, k * HID, HID);
    };

    // ---- build adjacency (bf16 {0,1}, exact) ----
    hipMemsetAsync(A0h, 0, (size_t)4096 * 4096 * 2, stream);
    build_adj_bf16<<<(E + 255) / 256, 256, 0, stream>>>(ei, E, A0h, 4096);

    // ---- down: level-0 GCN ----
    gcn(x0, 4096, 128, 256, nullptr, A0h, nullptr, Wd0, bd0, xs0, true, 1, 8);

    // ---- level 0 -> 1: pool + fused gathered augment ----
    pool(xs0, 4096, p1, perm1, xa);
    gatherG_bf16<<<(2048 * 4096) / 256, 256, 0, stream>>>(A0h, 4096, perm1, Gh, 2048);
    gemmBT(0, Gh, nullptr, Gh, nullptr, Cf, 2048, 2048, 4096, 2);
    aug_finish2<<<(2048 * 2048) / 256, 256, 0, stream>>>(Cf, A1f, A1h, nullptr, 2048);
    gcn(xa, 2048, 256, 256, A1f, A1h, nullptr, Wd1, bd1, xs1, true, 1, 8);

    // ---- level 1 -> 2 ----
    pool(xs1, 2048, p2, perm2, xa);
    gatherG_f32<<<(1024 * 2048) / 256, 256, 0, stream>>>(A1f, 2048, perm2, Gh, nullptr, 1024);
    gemmBT(0, Gh, nullptr, Gh, nullptr, Cf, 1024, 1024, 2048, 4);
    aug_finish2<<<(1024 * 1024) / 256, 256, 0, stream>>>(Cf, A2f, A2h, A2l, 1024);
    gcn(xa, 1024, 256, 256, A2f, A2h, A2l, Wd2, bd2, xs2, true, 2, 8);

    // ---- level 2 -> 3 ----
    pool(xs2, 1024, p3, perm3, xa);
    gatherG_f32<<<(512 * 1024) / 256, 256, 0, stream>>>(A2f, 1024, perm3, Gh, Gl, 512);
    gemmBT(2, Gh, Gl, Gh, Gl, Cf, 512, 512, 1024, 8);
    aug_finish2<<<(512 * 512) / 256, 256, 0, stream>>>(Cf, A3f, A3h, A3l, 512);
    gcn(xa, 512, 256, 256, A3f, A3h, A3l, Wd3, bd3, xb, true, 2, 8);

    // ---- up 0 (j=2) ----
    hipMemcpyAsync(xu, xs2, (size_t)1024 * 256 * 4, hipMemcpyDeviceToDevice, stream);
    scatter_add_kernel<<<(512 * 256) / 256, 256, 0, stream>>>(xu, xb, perm3, 512 * 256, 256);
    gcn(xu, 1024, 256, 256, A2f, A2h, A2l, Wu0, bu0, xa, true, 2, 8);

    // ---- up 1 (j=1) ----
    hipMemcpyAsync(xu, xs1, (size_t)2048 * 256 * 4, hipMemcpyDeviceToDevice, stream);
    scatter_add_kernel<<<(1024 * 256) / 256, 256, 0, stream>>>(xu, xa, perm2, 1024 * 256, 256);
    gcn(xu, 2048, 256, 256, A1f, A1h, nullptr, Wu1, bu1, xb, true, 1, 8);

    // ---- up 2 (j=0): final, no relu, Cout=128, straight to d_out ----
    hipMemcpyAsync(xu, xs0, (size_t)4096 * 256 * 4, hipMemcpyDeviceToDevice, stream);
    scatter_add_kernel<<<(2048 * 256) / 256, 256, 0, stream>>>(xu, xb, perm1, 2048 * 256, 256);
    gcn(xu, 4096, 256, 128, nullptr, A0h, nullptr, Wu2, bu2, (float*)d_out, false, 1, 8);
}

// Round 3
// 677.343 us; speedup vs baseline: 1.8586x; 1.1601x over previous
//
#include <hip/hip_runtime.h>

// ---------------------------------------------------------------------------
// GraphUNet on MI355X.  N=4096, IN_C=128, HID=256, OUT_C=128, DEPTH=3,
// KS={2048,1024,512}.
//
// Round-3 structure:
//  * rank-based top-k (O(n^2) over 256 CUs) replaces single-block bitonic.
//  * G@G^T computes upper-triangle blocks only; mirrored in aug_finish.
//  * split-K GEMMs write per-slice partials; consumers reduce (no memset,
//    no atomics on C).
//  * sts fused into x@W epilogue; rowsum fused into aug_finish; up-scatter
//    fused into gcn_final.  ~45 dispatches total.
// ---------------------------------------------------------------------------

typedef __attribute__((ext_vector_type(8))) short bf16x8;
typedef __attribute__((ext_vector_type(4))) float f32x4;

__device__ __forceinline__ short f2bf(float f) {
    unsigned u = __builtin_bit_cast(unsigned, f);
    u += 0x7FFFu + ((u >> 16) & 1u);          // RNE
    return (short)(u >> 16);
}
__device__ __forceinline__ float bf2f(short s) {
    unsigned u = ((unsigned)(unsigned short)s) << 16;
    return __builtin_bit_cast(float, u);
}

#define GLL16(gsrc, ldst)                                                        \
    __builtin_amdgcn_global_load_lds(                                            \
        (__attribute__((address_space(1))) void*)(gsrc),                         \
        (__attribute__((address_space(3))) void*)(ldst), 16, 0, 0)

// ---------------------------------------------------------------------------
// bf16 BT GEMM: Cslice(MxN) = A(MxK) @ B^T, B stored N x K row-major.
// Writes partials to Cp + z*M*N (no atomics). TRI: skip blocks by>bx.
// MODE 0: Ah@Bh ; 1: +Ah@Bl ; 2: +Al@Bh.
// ---------------------------------------------------------------------------
template<int MODE, bool TRI>
__global__ __launch_bounds__(256, 2)
void gemm_bt(const short* __restrict__ Ah, const short* __restrict__ Al,
             const short* __restrict__ Bh, const short* __restrict__ Bl,
             float* __restrict__ Cp, int M, int N, int K, int kChunk)
{
    if (TRI && (int)blockIdx.y > (int)blockIdx.x) return;

    __shared__ short sAh[128 * 32];
    __shared__ short sBh[128 * 32];
    __shared__ short sAl[(MODE == 2) ? 128 * 32 : 8];
    __shared__ short sBl[(MODE >= 1) ? 128 * 32 : 8];

    const int t    = threadIdx.x;
    const int lane = t & 63;
    const int wave = t >> 6;
    const int tM   = blockIdx.y * 128;
    const int tN   = blockIdx.x * 128;
    const int k0   = blockIdx.z * kChunk;

    const int wm  = (wave >> 1) * 64;
    const int wn  = (wave & 1) * 64;
    const int l15 = lane & 15;
    const int g8  = (lane >> 4) * 8;

    f32x4 acc[4][4];
    const f32x4 zero = {0.f, 0.f, 0.f, 0.f};
#pragma unroll
    for (int i = 0; i < 4; i++)
#pragma unroll
        for (int j = 0; j < 4; j++) acc[i][j] = zero;

    const int i0 = t, i1 = t + 256;
    const short* a0 = Ah + (size_t)(tM + (i0 >> 2)) * K + (i0 & 3) * 8;
    const short* a1 = Ah + (size_t)(tM + (i1 >> 2)) * K + (i1 & 3) * 8;
    const short* b0 = Bh + (size_t)(tN + (i0 >> 2)) * K + (i0 & 3) * 8;
    const short* b1 = Bh + (size_t)(tN + (i1 >> 2)) * K + (i1 & 3) * 8;
    const short *bl0 = nullptr, *bl1 = nullptr, *al0 = nullptr, *al1 = nullptr;
    if (MODE >= 1) {
        bl0 = Bl + (size_t)(tN + (i0 >> 2)) * K + (i0 & 3) * 8;
        bl1 = Bl + (size_t)(tN + (i1 >> 2)) * K + (i1 & 3) * 8;
    }
    if (MODE == 2) {
        al0 = Al + (size_t)(tM + (i0 >> 2)) * K + (i0 & 3) * 8;
        al1 = Al + (size_t)(tM + (i1 >> 2)) * K + (i1 & 3) * 8;
    }

    for (int kb = k0; kb < k0 + kChunk; kb += 32) {
        GLL16(a0 + kb, &sAh[i0 * 8]);
        GLL16(a1 + kb, &sAh[i1 * 8]);
        GLL16(b0 + kb, &sBh[i0 * 8]);
        GLL16(b1 + kb, &sBh[i1 * 8]);
        if (MODE >= 1) { GLL16(bl0 + kb, &sBl[i0 * 8]); GLL16(bl1 + kb, &sBl[i1 * 8]); }
        if (MODE == 2) { GLL16(al0 + kb, &sAl[i0 * 8]); GLL16(al1 + kb, &sAl[i1 * 8]); }
        __syncthreads();

        bf16x8 aF[4], bF[4], aL[4], bL[4];
#pragma unroll
        for (int i = 0; i < 4; i++)
            aF[i] = *(const bf16x8*)&sAh[(wm + i * 16 + l15) * 32 + g8];
#pragma unroll
        for (int j = 0; j < 4; j++)
            bF[j] = *(const bf16x8*)&sBh[(wn + j * 16 + l15) * 32 + g8];
        if (MODE >= 1)
#pragma unroll
            for (int j = 0; j < 4; j++)
                bL[j] = *(const bf16x8*)&sBl[(wn + j * 16 + l15) * 32 + g8];
        if (MODE == 2)
#pragma unroll
            for (int i = 0; i < 4; i++)
                aL[i] = *(const bf16x8*)&sAl[(wm + i * 16 + l15) * 32 + g8];

#pragma unroll
        for (int i = 0; i < 4; i++)
#pragma unroll
            for (int j = 0; j < 4; j++) {
                acc[i][j] = __builtin_amdgcn_mfma_f32_16x16x32_bf16(aF[i], bF[j], acc[i][j], 0, 0, 0);
                if (MODE >= 1)
                    acc[i][j] = __builtin_amdgcn_mfma_f32_16x16x32_bf16(aF[i], bL[j], acc[i][j], 0, 0, 0);
                if (MODE == 2)
                    acc[i][j] = __builtin_amdgcn_mfma_f32_16x16x32_bf16(aL[i], bF[j], acc[i][j], 0, 0, 0);
            }
        __syncthreads();
    }

    float* Cg = Cp + (size_t)blockIdx.z * M * N;
    const int r4 = (lane >> 4) * 4;
#pragma unroll
    for (int i = 0; i < 4; i++)
#pragma unroll
        for (int j = 0; j < 4; j++) {
            const int col = tN + wn + j * 16 + l15;
            float* cp = Cg + (size_t)(tM + wm + i * 16 + r4) * N + col;
#pragma unroll
            for (int r = 0; r < 4; r++) cp[(size_t)r * N] = acc[i][j][r];
        }
}

// ---------------------------------------------------------------------------
// fp32-input GEMM for x@W (3-pass hi/lo) with fused epilogue:
// writes xw (MxN) and Z^T hi/lo with Zt[c*M + r] = split(xw[r][c]/sqrt(rs[r]+2))
// ---------------------------------------------------------------------------
#define KPAD 40
__global__ __launch_bounds__(256, 2)
void gemm_xw(const float* __restrict__ X, const float* __restrict__ W,
             float* __restrict__ xw, short* __restrict__ Zh, short* __restrict__ Zl,
             const float* __restrict__ rs, int M, int N, int K)
{
    __shared__ short Ahs[128 * KPAD];
    __shared__ short Bhs[128 * KPAD];
    __shared__ short Als[128 * KPAD];
    __shared__ short Bls[128 * KPAD];

    const int t    = threadIdx.x;
    const int lane = t & 63;
    const int wave = t >> 6;
    const int tM   = blockIdx.y * 128;
    const int tN   = blockIdx.x * 128;

    const int wm  = (wave >> 1) * 64;
    const int wn  = (wave & 1) * 64;
    const int l15 = lane & 15;
    const int g8  = (lane >> 4) * 8;

    f32x4 acc[4][4];
    const f32x4 zero = {0.f, 0.f, 0.f, 0.f};
#pragma unroll
    for (int i = 0; i < 4; i++)
#pragma unroll
        for (int j = 0; j < 4; j++) acc[i][j] = zero;

    const int am = t >> 1;
    const int ak = (t & 1) * 16;
    const int bn = t & 127;
    const int bk = (t >> 7) * 16;

    const float* aSrc = X + (size_t)(tM + am) * K + ak;
    const float* bSrc = W + (size_t)bk * N + tN + bn;

    for (int kb = 0; kb < K; kb += 32) {
        {
            const float* src = aSrc + kb;
            float v[16];
#pragma unroll
            for (int q = 0; q < 4; q++) {
                const float4 f = *(const float4*)(src + 4 * q);
                v[4*q] = f.x; v[4*q+1] = f.y; v[4*q+2] = f.z; v[4*q+3] = f.w;
            }
            short h[16], l[16];
#pragma unroll
            for (int q = 0; q < 16; q++) { h[q] = f2bf(v[q]); l[q] = f2bf(v[q] - bf2f(h[q])); }
            *(bf16x8*)&Ahs[am * KPAD + ak]     = *(bf16x8*)&h[0];
            *(bf16x8*)&Ahs[am * KPAD + ak + 8] = *(bf16x8*)&h[8];
            *(bf16x8*)&Als[am * KPAD + ak]     = *(bf16x8*)&l[0];
            *(bf16x8*)&Als[am * KPAD + ak + 8] = *(bf16x8*)&l[8];
        }
        {
            const float* src = bSrc + (size_t)kb * N;
            float v[16];
#pragma unroll
            for (int q = 0; q < 16; q++) v[q] = src[(size_t)q * N];
            short h[16], l[16];
#pragma unroll
            for (int q = 0; q < 16; q++) { h[q] = f2bf(v[q]); l[q] = f2bf(v[q] - bf2f(h[q])); }
            *(bf16x8*)&Bhs[bn * KPAD + bk]     = *(bf16x8*)&h[0];
            *(bf16x8*)&Bhs[bn * KPAD + bk + 8] = *(bf16x8*)&h[8];
            *(bf16x8*)&Bls[bn * KPAD + bk]     = *(bf16x8*)&l[0];
            *(bf16x8*)&Bls[bn * KPAD + bk + 8] = *(bf16x8*)&l[8];
        }
        __syncthreads();

        bf16x8 aF[4], bF[4], aL2[4], bL2[4];
#pragma unroll
        for (int i = 0; i < 4; i++) {
            aF[i]  = *(const bf16x8*)&Ahs[(wm + i * 16 + l15) * KPAD + g8];
            aL2[i] = *(const bf16x8*)&Als[(wm + i * 16 + l15) * KPAD + g8];
        }
#pragma unroll
        for (int j = 0; j < 4; j++) {
            bF[j]  = *(const bf16x8*)&Bhs[(wn + j * 16 + l15) * KPAD + g8];
            bL2[j] = *(const bf16x8*)&Bls[(wn + j * 16 + l15) * KPAD + g8];
        }

#pragma unroll
        for (int i = 0; i < 4; i++)
#pragma unroll
            for (int j = 0; j < 4; j++) {
                acc[i][j] = __builtin_amdgcn_mfma_f32_16x16x32_bf16(aF[i],  bF[j],  acc[i][j], 0, 0, 0);
                acc[i][j] = __builtin_amdgcn_mfma_f32_16x16x32_bf16(aF[i],  bL2[j], acc[i][j], 0, 0, 0);
                acc[i][j] = __builtin_amdgcn_mfma_f32_16x16x32_bf16(aL2[i], bF[j],  acc[i][j], 0, 0, 0);
            }
        __syncthreads();
    }

    const int r4 = (lane >> 4) * 4;
#pragma unroll
    for (int i = 0; i < 4; i++) {
        const int rbase = tM + wm + i * 16 + r4;
        float dd[4];
#pragma unroll
        for (int r = 0; r < 4; r++) dd[r] = 1.f / sqrtf(rs[rbase + r] + 2.f);
#pragma unroll
        for (int j = 0; j < 4; j++) {
            const int c = tN + wn + j * 16 + l15;
            unsigned short zh[4], zl[4];
#pragma unroll
            for (int r = 0; r < 4; r++) {
                float v = acc[i][j][r];
                xw[(size_t)(rbase + r) * N + c] = v;
                float z = v * dd[r];
                short h = f2bf(z);
                zh[r] = (unsigned short)h;
                zl[r] = (unsigned short)f2bf(z - bf2f(h));
            }
            uint2 ph, pl;
            ph.x = (unsigned)zh[0] | ((unsigned)zh[1] << 16);
            ph.y = (unsigned)zh[2] | ((unsigned)zh[3] << 16);
            pl.x = (unsigned)zl[0] | ((unsigned)zl[1] << 16);
            pl.y = (unsigned)zl[2] | ((unsigned)zl[3] << 16);
            *(uint2*)&Zh[(size_t)c * M + rbase] = ph;
            *(uint2*)&Zl[(size_t)c * M + rbase] = pl;
        }
    }
}

// ---------------------------------------------------------------------------
// Utility kernels
// ---------------------------------------------------------------------------

__global__ void build_adj_bf16(const int* __restrict__ ei, int E,
                               short* __restrict__ A, int n)
{
    int e = blockIdx.x * 256 + threadIdx.x;
    if (e >= E) return;
    int i = ei[e], j = ei[E + e];
    if (i != j) {
        A[(size_t)i * n + j] = (short)0x3F80;
        A[(size_t)j * n + i] = (short)0x3F80;
    }
}

// raw row sums of bf16 A
__global__ void rowsum_bf16(const short* __restrict__ A, int n,
                            float* __restrict__ rs)
{
    int row = blockIdx.x * 4 + (threadIdx.x >> 6);
    int lane = threadIdx.x & 63;
    const ushort4* ar = (const ushort4*)(A + (size_t)row * n);
    float s = 0.f;
    for (int c = lane; c < (n >> 2); c += 64) {
        ushort4 u = ar[c];
        s += bf2f((short)u.x) + bf2f((short)u.y) + bf2f((short)u.z) + bf2f((short)u.w);
    }
    for (int off = 32; off; off >>= 1) s += __shfl_down(s, off);
    if (lane == 0) rs[row] = s;
}

// gcn_final: reduce S split-K slices + GCN epilogue (+optional scatter-add)
__global__ void gcn_final(const float* __restrict__ Cp, int S,
                          const float* __restrict__ xw, const float* __restrict__ rs,
                          const float* __restrict__ b, float* __restrict__ out,
                          int nrows, int C, int relu, const int* __restrict__ perm)
{
    int t = blockIdx.x * 256 + threadIdx.x;
    int i = t / C, c = t - i * C;
    size_t stride = (size_t)nrows * C;
    float az = 0.f;
    for (int s = 0; s < S; s++) az += Cp[t + s * stride];
    float d = 1.f / sqrtf(rs[i] + 2.f);
    float v = d * az + 2.f * d * d * xw[t] + b[c];
    if (relu && v < 0.f) v = 0.f;
    if (perm) out[(size_t)perm[i] * C + c] += v;
    else      out[t] = v;
}

// per-row score = tanh(x.p / ||p||), one wave per row, norm computed in-wave
__global__ void score_kernel(const float* __restrict__ x,
                             const float* __restrict__ p,
                             float* __restrict__ score, int n)
{
    int row = blockIdx.x * 4 + (threadIdx.x >> 6);
    int lane = threadIdx.x & 63;
    float4 pv = ((const float4*)p)[lane];
    float4 xv = ((const float4*)(x + (size_t)row * 256))[lane];
    double nn  = (double)pv.x * pv.x + (double)pv.y * pv.y +
                 (double)pv.z * pv.z + (double)pv.w * pv.w;
    double acc = (double)xv.x * pv.x + (double)xv.y * pv.y +
                 (double)xv.z * pv.z + (double)xv.w * pv.w;
    for (int off = 32; off; off >>= 1) {
        acc += __shfl_down(acc, off);
        nn  += __shfl_down(nn, off);
    }
    if (lane == 0) score[row] = tanhf((float)(acc / sqrt(nn)));
}

// rank-based top-k: total order (score desc, idx asc) == jax.lax.top_k
__device__ __forceinline__ unsigned long long packkey(float s, int i) {
    unsigned u = __builtin_bit_cast(unsigned, s);
    u = (u & 0x80000000u) ? ~u : (u | 0x80000000u);
    return ((unsigned long long)u << 32) | (unsigned)(0xFFFFFFFFu - (unsigned)i);
}

__global__ __launch_bounds__(256)
void rank_topk(const float* __restrict__ score, int n, int k,
               int* __restrict__ perm, float* __restrict__ vals)
{
    __shared__ unsigned long long sk[1024];
    int i = blockIdx.x * 256 + threadIdx.x;
    float s = score[i];
    unsigned long long mykey = packkey(s, i);
    int rank = 0;
    for (int jt = 0; jt < n; jt += 1024) {
#pragma unroll
        for (int q = 0; q < 4; q++) {
            int idx = jt + threadIdx.x + q * 256;
            sk[threadIdx.x + q * 256] = packkey(score[idx], idx);
        }
        __syncthreads();
#pragma unroll 16
        for (int q = 0; q < 1024; q++) rank += (sk[q] > mykey) ? 1 : 0;
        __syncthreads();
    }
    if (rank < k) { perm[rank] = i; vals[rank] = s; }
}

__global__ void gather_x_kernel(const float* __restrict__ xold,
                                const int* __restrict__ perm,
                                const float* __restrict__ vals,
                                float* __restrict__ xnew, int total, int C)
{
    int t = blockIdx.x * 256 + threadIdx.x;
    if (t >= total) return;
    int r = t / C, c = t - r * C;
    xnew[t] = xold[(size_t)perm[r] * C + c] * vals[r];
}

// G = (A+I)[perm,:] from bf16 A (values small ints, exact); zeroes rs_next
__global__ void gatherG_h(const short* __restrict__ A, int n,
                          const int* __restrict__ perm,
                          short* __restrict__ Gh, int kk,
                          float* __restrict__ rsz)
{
    int t = blockIdx.x * 256 + threadIdx.x;
    if (t < kk) rsz[t] = 0.f;
    if (t >= kk * n) return;
    int r = t / n, c = t - r * n;
    int pr = perm[r];
    float v = bf2f(A[(size_t)pr * n + c]) + (c == pr ? 1.f : 0.f);
    Gh[t] = f2bf(v);
}

// G = (A+I)[perm,:] from hi/lo A -> hi/lo G; zeroes rs_next
__global__ void gatherG_hl(const short* __restrict__ Ahi, const short* __restrict__ Alo,
                           int n, const int* __restrict__ perm,
                           short* __restrict__ Gh, short* __restrict__ Gl, int kk,
                           float* __restrict__ rsz)
{
    int t = blockIdx.x * 256 + threadIdx.x;
    if (t < kk) rsz[t] = 0.f;
    if (t >= kk * n) return;
    int r = t / n, c = t - r * n;
    int pr = perm[r];
    float v = bf2f(Ahi[(size_t)pr * n + c]) + bf2f(Alo[(size_t)pr * n + c])
            + (c == pr ? 1.f : 0.f);
    short h = f2bf(v);
    Gh[t] = h;
    Gl[t] = f2bf(v - bf2f(h));
}

// A_next from S upper-triangle partial slices: mirror, zero diag, emit hi(/lo),
// accumulate row sums (wave-reduced atomics into pre-zeroed rs)
template<bool LO>
__global__ void aug_finish(const float* __restrict__ Cp, int S, int kk,
                           short* __restrict__ Ahs, short* __restrict__ Als,
                           float* __restrict__ rs)
{
    int t = blockIdx.x * 256 + threadIdx.x;
    int r = t / kk, c = t - r * kk;
    int rr = min(r, c), cc = max(r, c);
    size_t src = (size_t)rr * kk + cc;
    size_t stride = (size_t)kk * kk;
    float v = 0.f;
    for (int s = 0; s < S; s++) v += Cp[src + s * stride];
    if (r == c) v = 0.f;
    short h = f2bf(v);
    Ahs[t] = h;
    if (LO) Als[t] = f2bf(v - bf2f(h));
    float ws = v;
    for (int off = 32; off; off >>= 1) ws += __shfl_down(ws, off);
    if ((threadIdx.x & 63) == 0) atomicAdd(&rs[r], ws);
}

// ---------------------------------------------------------------------------
// Host orchestration
// ---------------------------------------------------------------------------

extern "C" void kernel_launch(void* const* d_in, const int* in_sizes, int n_in,
                              void* d_out, int out_size, void* d_ws, size_t ws_size,
                              hipStream_t stream)
{
    const float* x0  = (const float*)d_in[0];
    const int*   ei  = (const int*)d_in[1];
    const float* Wd0 = (const float*)d_in[2];  const float* bd0 = (const float*)d_in[3];
    const float* Wd1 = (const float*)d_in[4];  const float* bd1 = (const float*)d_in[5];
    const float* Wd2 = (const float*)d_in[6];  const float* bd2 = (const float*)d_in[7];
    const float* Wd3 = (const float*)d_in[8];  const float* bd3 = (const float*)d_in[9];
    const float* p1  = (const float*)d_in[10];
    const float* p2  = (const float*)d_in[11];
    const float* p3  = (const float*)d_in[12];
    const float* Wu0 = (const float*)d_in[13]; const float* bu0 = (const float*)d_in[14];
    const float* Wu1 = (const float*)d_in[15]; const float* bu1 = (const float*)d_in[16];
    const float* Wu2 = (const float*)d_in[17]; const float* bu2 = (const float*)d_in[18];

    const int E = in_sizes[1] / 2;

    char* ws = (char*)d_ws;
    size_t off = 0;
    auto alloc = [&](size_t bytes) -> void* {
        void* p = ws + off;
        off += (bytes + 255) & ~(size_t)255;
        return p;
    };
    short* A0h  = (short*)alloc((size_t)4096 * 4096 * 2);
    short* A1h  = (short*)alloc((size_t)2048 * 2048 * 2);
    short* A2h  = (short*)alloc((size_t)1024 * 1024 * 2);
    short* A2l  = (short*)alloc((size_t)1024 * 1024 * 2);
    short* A3h  = (short*)alloc((size_t)512 * 512 * 2);
    short* A3l  = (short*)alloc((size_t)512 * 512 * 2);
    short* Gh   = (short*)alloc((size_t)2048 * 4096 * 2);
    short* Gl   = (short*)alloc((size_t)512 * 1024 * 2);
    float* Cp   = (float*)alloc((size_t)8 * 4096 * 1024 * 4);   // 32 MB partials
    float* xs0  = (float*)alloc((size_t)4096 * 256 * 4);
    float* xs1  = (float*)alloc((size_t)2048 * 256 * 4);
    float* xs2  = (float*)alloc((size_t)1024 * 256 * 4);
    float* xwb  = (float*)alloc((size_t)4096 * 256 * 4);
    short* Zh   = (short*)alloc((size_t)256 * 4096 * 2);
    short* Zl   = (short*)alloc((size_t)256 * 4096 * 2);
    float* xa   = (float*)alloc((size_t)2048 * 256 * 4);
    float* xu0  = (float*)alloc((size_t)4096 * 256 * 4);
    float* xu1  = (float*)alloc((size_t)2048 * 256 * 4);
    float* xu2  = (float*)alloc((size_t)1024 * 256 * 4);
    float* rs0  = (float*)alloc(4096 * 4);
    float* rs1  = (float*)alloc(2048 * 4);
    float* rs2  = (float*)alloc(1024 * 4);
    float* rs3  = (float*)alloc(512 * 4);
    float* scoreb = (float*)alloc(4096 * 4);
    float* valsb  = (float*)alloc(2048 * 4);
    int*   perm1  = (int*)alloc(2048 * 4);
    int*   perm2  = (int*)alloc(1024 * 4);
    int*   perm3  = (int*)alloc(512 * 4);

    // AZ GEMM: Cp slices = A @ Z (Z^T stored Cout x n hi/lo), S=8
    auto az = [&](int mode, const short* pAh, const short* pAl, int n, int Cout) {
        dim3 g(Cout / 128, n / 128, 8);
        int kChunk = n / 8;
        if (mode == 1) gemm_bt<1, false><<<g, 256, 0, stream>>>(pAh, nullptr, Zh, Zl, Cp, n, Cout, n, kChunk);
        else           gemm_bt<2, false><<<g, 256, 0, stream>>>(pAh, pAl,     Zh, Zl, Cp, n, Cout, n, kChunk);
    };

    // full GCN layer
    auto gcn = [&](const float* xin, int n, int Kc, int Cout,
                   const short* pAh, const short* pAl, const float* rsA,
                   const float* W, const float* b, float* out, int relu,
                   int mode, const int* perm) {
        gemm_xw<<<dim3(Cout / 128, n / 128), 256, 0, stream>>>(xin, W, xwb, Zh, Zl, rsA, n, Cout, Kc);
        az(mode, pAh, pAl, n, Cout);
        gcn_final<<<(n * Cout) / 256, 256, 0, stream>>>(Cp, 8, xwb, rsA, b, out, n, Cout, relu, perm);
    };

    auto pool = [&](const float* xlev, int n, const float* p, int* perm, float* xout) {
        int k = n / 2;
        score_kernel<<<n / 4, 256, 0, stream>>>(xlev, p, scoreb, n);
        rank_topk<<<n / 256, 256, 0, stream>>>(scoreb, n, k, perm, valsb);
        gather_x_kernel<<<k, 256, 0, stream>>>(xlev, perm, valsb, xout, k * 256, 256);
    };

    // ---- build adjacency ----
    hipMemsetAsync(A0h, 0, (size_t)4096 * 4096 * 2, stream);
    build_adj_bf16<<<(E + 255) / 256, 256, 0, stream>>>(ei, E, A0h, 4096);
    rowsum_bf16<<<1024, 256, 0, stream>>>(A0h, 4096, rs0);

    // ---- down 0 ----
    gcn(x0, 4096, 128, 256, A0h, nullptr, rs0, Wd0, bd0, xs0, 1, 1, nullptr);

    // ---- level 0 -> 1 ----
    pool(xs0, 4096, p1, perm1, xa);
    gatherG_h<<<(2048 * 4096) / 256, 256, 0, stream>>>(A0h, 4096, perm1, Gh, 2048, rs1);
    gemm_bt<0, true><<<dim3(16, 16, 2), 256, 0, stream>>>(Gh, nullptr, Gh, nullptr, Cp, 2048, 2048, 4096, 2048);
    aug_finish<false><<<(2048 * 2048) / 256, 256, 0, stream>>>(Cp, 2, 2048, A1h, nullptr, rs1);
    gcn(xa, 2048, 256, 256, A1h, nullptr, rs1, Wd1, bd1, xs1, 1, 1, nullptr);

    // ---- level 1 -> 2 ----
    pool(xs1, 2048, p2, perm2, xa);
    gatherG_h<<<(1024 * 2048) / 256, 256, 0, stream>>>(A1h, 2048, perm2, Gh, 1024, rs2);
    gemm_bt<0, true><<<dim3(8, 8, 8), 256, 0, stream>>>(Gh, nullptr, Gh, nullptr, Cp, 1024, 1024, 2048, 256);
    aug_finish<true><<<(1024 * 1024) / 256, 256, 0, stream>>>(Cp, 8, 1024, A2h, A2l, rs2);
    gcn(xa, 1024, 256, 256, A2h, A2l, rs2, Wd2, bd2, xs2, 1, 2, nullptr);

    // ---- level 2 -> 3 ----
    pool(xs2, 1024, p3, perm3, xa);
    gatherG_hl<<<(512 * 1024) / 256, 256, 0, stream>>>(A2h, A2l, 1024, perm3, Gh, Gl, 512, rs3);
    gemm_bt<2, true><<<dim3(4, 4, 8), 256, 0, stream>>>(Gh, Gl, Gh, Gl, Cp, 512, 512, 1024, 128);
    aug_finish<true><<<(512 * 512) / 256, 256, 0, stream>>>(Cp, 8, 512, A3h, A3l, rs3);

    // ---- down 3, scattered into xu2 = xs2 + u ----
    hipMemcpyAsync(xu2, xs2, (size_t)1024 * 256 * 4, hipMemcpyDeviceToDevice, stream);
    gcn(xa, 512, 256, 256, A3h, A3l, rs3, Wd3, bd3, xu2, 1, 2, perm3);

    // ---- up 0 (n=1024, A2), scattered into xu1 = xs1 + u ----
    hipMemcpyAsync(xu1, xs1, (size_t)2048 * 256 * 4, hipMemcpyDeviceToDevice, stream);
    gcn(xu2, 1024, 256, 256, A2h, A2l, rs2, Wu0, bu0, xu1, 1, 2, perm2);

    // ---- up 1 (n=2048, A1), scattered into xu0 = xs0 + u ----
    hipMemcpyAsync(xu0, xs0, (size_t)4096 * 256 * 4, hipMemcpyDeviceToDevice, stream);
    gcn(xu1, 2048, 256, 256, A1h, nullptr, rs1, Wu1, bu1, xu0, 1, 1, perm1);

    // ---- up 2 (n=4096, A0, Cout=128, no relu) -> d_out ----
    gcn(xu0, 4096, 256, 128, A0h, nullptr, rs0, Wu2, bu2, (float*)d_out, 0, 1, nullptr);
}

// Round 4
// 676.307 us; speedup vs baseline: 1.8614x; 1.0015x over previous
//
#include <hip/hip_runtime.h>

// ---------------------------------------------------------------------------
// GraphUNet on MI355X.  N=4096, IN_C=128, HID=256, OUT_C=128, DEPTH=3,
// KS={2048,1024,512}.
//
// Round-4 structure:
//  * TRI GEMM epilogue writes BOTH mirror halves (float4 transposed stores);
//    aug_finish is now a coalesced streaming reduce.
//  * every heavy GEMM (incl. x@W) uses the global_load_lds BT kernel;
//    hi/lo operand splits are produced in producer epilogues.
//  * S=4 split-K for the n=4096 A@Z GEMMs.
// ---------------------------------------------------------------------------

typedef __attribute__((ext_vector_type(8))) short bf16x8;
typedef __attribute__((ext_vector_type(4))) float f32x4;

__device__ __forceinline__ short f2bf(float f) {
    unsigned u = __builtin_bit_cast(unsigned, f);
    u += 0x7FFFu + ((u >> 16) & 1u);          // RNE
    return (short)(u >> 16);
}
__device__ __forceinline__ float bf2f(short s) {
    unsigned u = ((unsigned)(unsigned short)s) << 16;
    return __builtin_bit_cast(float, u);
}

#define GLL16(gsrc, ldst)                                                        \
    __builtin_amdgcn_global_load_lds(                                            \
        (__attribute__((address_space(1))) void*)(gsrc),                         \
        (__attribute__((address_space(3))) void*)(ldst), 16, 0, 0)

// ---------------------------------------------------------------------------
// bf16 BT GEMM: C(MxN) = A(MxK) @ B^T, B stored N x K row-major.
// MODE 0: Ah@Bh ; 1: +Ah@Bl ; 2: +Al@Bh   (lo*lo dropped, ~2^-18 rel)
// EPI 0: write fp32 partial slice at Cf + z*M*N
// EPI 1: EPI0 + transposed tile to mirror block (square M==N, TRI grids;
//        blocks with by>bx exit immediately)
// EPI 2: xw fp32 (MxN) + Z^T hi/lo, Zt[c*M+r] = split(xw[r][c]/sqrt(rs[r]+2))
// ---------------------------------------------------------------------------
template<int MODE, int EPI>
__global__ __launch_bounds__(256, 2)
void gemm_bt(const short* __restrict__ Ah, const short* __restrict__ Al,
             const short* __restrict__ Bh, const short* __restrict__ Bl,
             float* __restrict__ Cf, short* __restrict__ Eh, short* __restrict__ El,
             const float* __restrict__ rs, int M, int N, int K, int kChunk)
{
    if (EPI == 1 && (int)blockIdx.y > (int)blockIdx.x) return;

    __shared__ short sAh[128 * 32];
    __shared__ short sBh[128 * 32];
    __shared__ short sAl[(MODE == 2) ? 128 * 32 : 8];
    __shared__ short sBl[(MODE >= 1) ? 128 * 32 : 8];

    const int t    = threadIdx.x;
    const int lane = t & 63;
    const int wave = t >> 6;
    const int tM   = blockIdx.y * 128;
    const int tN   = blockIdx.x * 128;
    const int k0   = blockIdx.z * kChunk;

    const int wm  = (wave >> 1) * 64;
    const int wn  = (wave & 1) * 64;
    const int l15 = lane & 15;
    const int g8  = (lane >> 4) * 8;

    f32x4 acc[4][4];
    const f32x4 zero = {0.f, 0.f, 0.f, 0.f};
#pragma unroll
    for (int i = 0; i < 4; i++)
#pragma unroll
        for (int j = 0; j < 4; j++) acc[i][j] = zero;

    const int i0 = t, i1 = t + 256;
    const short* a0 = Ah + (size_t)(tM + (i0 >> 2)) * K + (i0 & 3) * 8;
    const short* a1 = Ah + (size_t)(tM + (i1 >> 2)) * K + (i1 & 3) * 8;
    const short* b0 = Bh + (size_t)(tN + (i0 >> 2)) * K + (i0 & 3) * 8;
    const short* b1 = Bh + (size_t)(tN + (i1 >> 2)) * K + (i1 & 3) * 8;
    const short *bl0 = nullptr, *bl1 = nullptr, *al0 = nullptr, *al1 = nullptr;
    if (MODE >= 1) {
        bl0 = Bl + (size_t)(tN + (i0 >> 2)) * K + (i0 & 3) * 8;
        bl1 = Bl + (size_t)(tN + (i1 >> 2)) * K + (i1 & 3) * 8;
    }
    if (MODE == 2) {
        al0 = Al + (size_t)(tM + (i0 >> 2)) * K + (i0 & 3) * 8;
        al1 = Al + (size_t)(tM + (i1 >> 2)) * K + (i1 & 3) * 8;
    }

    for (int kb = k0; kb < k0 + kChunk; kb += 32) {
        GLL16(a0 + kb, &sAh[i0 * 8]);
        GLL16(a1 + kb, &sAh[i1 * 8]);
        GLL16(b0 + kb, &sBh[i0 * 8]);
        GLL16(b1 + kb, &sBh[i1 * 8]);
        if (MODE >= 1) { GLL16(bl0 + kb, &sBl[i0 * 8]); GLL16(bl1 + kb, &sBl[i1 * 8]); }
        if (MODE == 2) { GLL16(al0 + kb, &sAl[i0 * 8]); GLL16(al1 + kb, &sAl[i1 * 8]); }
        __syncthreads();

        bf16x8 aF[4], bF[4], aL[4], bL[4];
#pragma unroll
        for (int i = 0; i < 4; i++)
            aF[i] = *(const bf16x8*)&sAh[(wm + i * 16 + l15) * 32 + g8];
#pragma unroll
        for (int j = 0; j < 4; j++)
            bF[j] = *(const bf16x8*)&sBh[(wn + j * 16 + l15) * 32 + g8];
        if (MODE >= 1)
#pragma unroll
            for (int j = 0; j < 4; j++)
                bL[j] = *(const bf16x8*)&sBl[(wn + j * 16 + l15) * 32 + g8];
        if (MODE == 2)
#pragma unroll
            for (int i = 0; i < 4; i++)
                aL[i] = *(const bf16x8*)&sAl[(wm + i * 16 + l15) * 32 + g8];

#pragma unroll
        for (int i = 0; i < 4; i++)
#pragma unroll
            for (int j = 0; j < 4; j++) {
                acc[i][j] = __builtin_amdgcn_mfma_f32_16x16x32_bf16(aF[i], bF[j], acc[i][j], 0, 0, 0);
                if (MODE >= 1)
                    acc[i][j] = __builtin_amdgcn_mfma_f32_16x16x32_bf16(aF[i], bL[j], acc[i][j], 0, 0, 0);
                if (MODE == 2)
                    acc[i][j] = __builtin_amdgcn_mfma_f32_16x16x32_bf16(aL[i], bF[j], acc[i][j], 0, 0, 0);
            }
        __syncthreads();
    }

    const int r4 = (lane >> 4) * 4;
    if (EPI == 2) {
        // xw + Z^T hi/lo epilogue (C/D layout: col=lane&15, row=(lane>>4)*4+reg)
#pragma unroll
        for (int i = 0; i < 4; i++) {
            const int rbase = tM + wm + i * 16 + r4;
            float dd[4];
#pragma unroll
            for (int r = 0; r < 4; r++) dd[r] = 1.f / sqrtf(rs[rbase + r] + 2.f);
#pragma unroll
            for (int j = 0; j < 4; j++) {
                const int c = tN + wn + j * 16 + l15;
                unsigned short zh[4], zl[4];
#pragma unroll
                for (int r = 0; r < 4; r++) {
                    float v = acc[i][j][r];
                    Cf[(size_t)(rbase + r) * N + c] = v;
                    float z = v * dd[r];
                    short h = f2bf(z);
                    zh[r] = (unsigned short)h;
                    zl[r] = (unsigned short)f2bf(z - bf2f(h));
                }
                uint2 ph, pl;
                ph.x = (unsigned)zh[0] | ((unsigned)zh[1] << 16);
                ph.y = (unsigned)zh[2] | ((unsigned)zh[3] << 16);
                pl.x = (unsigned)zl[0] | ((unsigned)zl[1] << 16);
                pl.y = (unsigned)zl[2] | ((unsigned)zl[3] << 16);
                *(uint2*)&Eh[(size_t)c * M + rbase] = ph;
                *(uint2*)&El[(size_t)c * M + rbase] = pl;
            }
        }
    } else {
        float* Cg = Cf + (size_t)blockIdx.z * M * N;
#pragma unroll
        for (int i = 0; i < 4; i++)
#pragma unroll
            for (int j = 0; j < 4; j++) {
                const int col = tN + wn + j * 16 + l15;
                float* cp = Cg + (size_t)(tM + wm + i * 16 + r4) * N + col;
#pragma unroll
                for (int r = 0; r < 4; r++) cp[(size_t)r * N] = acc[i][j][r];
            }
        if (EPI == 1 && tM != tN) {
            // mirror: transposed tile to block (bx,by); rows contiguous -> float4
#pragma unroll
            for (int i = 0; i < 4; i++)
#pragma unroll
                for (int j = 0; j < 4; j++) {
                    const int col   = tN + wn + j * 16 + l15;
                    const int rbase = tM + wm + i * 16 + r4;
                    *(f32x4*)&Cg[(size_t)col * N + rbase] = acc[i][j];
                }
        }
    }
}

// ---------------------------------------------------------------------------
// Utility kernels
// ---------------------------------------------------------------------------

__global__ void build_adj_bf16(const int* __restrict__ ei, int E,
                               short* __restrict__ A, int n)
{
    int e = blockIdx.x * 256 + threadIdx.x;
    if (e >= E) return;
    int i = ei[e], j = ei[E + e];
    if (i != j) {
        A[(size_t)i * n + j] = (short)0x3F80;
        A[(size_t)j * n + i] = (short)0x3F80;
    }
}

__global__ void rowsum_bf16(const short* __restrict__ A, int n,
                            float* __restrict__ rs)
{
    int row = blockIdx.x * 4 + (threadIdx.x >> 6);
    int lane = threadIdx.x & 63;
    const ushort4* ar = (const ushort4*)(A + (size_t)row * n);
    float s = 0.f;
    for (int c = lane; c < (n >> 2); c += 64) {
        ushort4 u = ar[c];
        s += bf2f((short)u.x) + bf2f((short)u.y) + bf2f((short)u.z) + bf2f((short)u.w);
    }
    for (int off = 32; off; off >>= 1) s += __shfl_down(s, off);
    if (lane == 0) rs[row] = s;
}

// x0 -> hi/lo split (row-major preserved)
__global__ void split_rows(const float* __restrict__ x,
                           short* __restrict__ Xh, short* __restrict__ Xl, int total)
{
    int t = blockIdx.x * 256 + threadIdx.x;
    if (t >= total) return;
    float v = x[t];
    short h = f2bf(v);
    Xh[t] = h;
    Xl[t] = f2bf(v - bf2f(h));
}

// W (KxN) -> W^T hi/lo (NxK)
__global__ void wsplit(const float* __restrict__ W,
                       short* __restrict__ Wth, short* __restrict__ Wtl,
                       int K, int N)
{
    int t = blockIdx.x * 256 + threadIdx.x;
    if (t >= K * N) return;
    int k = t / N, n = t - k * N;
    float v = W[t];
    short h = f2bf(v);
    Wth[(size_t)n * K + k] = h;
    Wtl[(size_t)n * K + k] = f2bf(v - bf2f(h));
}

// gcn_final: reduce S slices + GCN epilogue, emit fp32 + hi/lo (+perm scatter)
__global__ void gcn_final(const float* __restrict__ Cp, int S,
                          const float* __restrict__ xw, const float* __restrict__ rs,
                          const float* __restrict__ b, float* __restrict__ out,
                          short* __restrict__ oh, short* __restrict__ ol,
                          int nrows, int C, int relu, const int* __restrict__ perm)
{
    int t = blockIdx.x * 256 + threadIdx.x;
    int i = t / C, c = t - i * C;
    size_t stride = (size_t)nrows * C;
    float az = 0.f;
    for (int s = 0; s < S; s++) az += Cp[t + s * stride];
    float d = 1.f / sqrtf(rs[i] + 2.f);
    float v = d * az + 2.f * d * d * xw[t] + b[c];
    if (relu && v < 0.f) v = 0.f;
    size_t o = perm ? ((size_t)perm[i] * C + c) : (size_t)t;
    if (perm) v += out[o];
    out[o] = v;
    if (oh) {
        short h = f2bf(v);
        oh[o] = h;
        ol[o] = f2bf(v - bf2f(h));
    }
}

__global__ void score_kernel(const float* __restrict__ x,
                             const float* __restrict__ p,
                             float* __restrict__ score, int n)
{
    int row = blockIdx.x * 4 + (threadIdx.x >> 6);
    int lane = threadIdx.x & 63;
    float4 pv = ((const float4*)p)[lane];
    float4 xv = ((const float4*)(x + (size_t)row * 256))[lane];
    double nn  = (double)pv.x * pv.x + (double)pv.y * pv.y +
                 (double)pv.z * pv.z + (double)pv.w * pv.w;
    double acc = (double)xv.x * pv.x + (double)xv.y * pv.y +
                 (double)xv.z * pv.z + (double)xv.w * pv.w;
    for (int off = 32; off; off >>= 1) {
        acc += __shfl_down(acc, off);
        nn  += __shfl_down(nn, off);
    }
    if (lane == 0) score[row] = tanhf((float)(acc / sqrt(nn)));
}

__device__ __forceinline__ unsigned long long packkey(float s, int i) {
    unsigned u = __builtin_bit_cast(unsigned, s);
    u = (u & 0x80000000u) ? ~u : (u | 0x80000000u);
    return ((unsigned long long)u << 32) | (unsigned)(0xFFFFFFFFu - (unsigned)i);
}

__global__ __launch_bounds__(256)
void rank_topk(const float* __restrict__ score, int n, int k,
               int* __restrict__ perm, float* __restrict__ vals)
{
    __shared__ unsigned long long sk[1024];
    int i = blockIdx.x * 256 + threadIdx.x;
    float s = score[i];
    unsigned long long mykey = packkey(s, i);
    int rank = 0;
    for (int jt = 0; jt < n; jt += 1024) {
#pragma unroll
        for (int q = 0; q < 4; q++) {
            int idx = jt + threadIdx.x + q * 256;
            sk[threadIdx.x + q * 256] = packkey(score[idx], idx);
        }
        __syncthreads();
#pragma unroll 16
        for (int q = 0; q < 1024; q++) rank += (sk[q] > mykey) ? 1 : 0;
        __syncthreads();
    }
    if (rank < k) { perm[rank] = i; vals[rank] = s; }
}

// gathered+scaled x -> hi/lo only (consumed solely by the x@W GEMM)
__global__ void gather_x_hl(const float* __restrict__ xold,
                            const int* __restrict__ perm,
                            const float* __restrict__ vals,
                            short* __restrict__ Xh, short* __restrict__ Xl,
                            int total, int C)
{
    int t = blockIdx.x * 256 + threadIdx.x;
    if (t >= total) return;
    int r = t / C, c = t - r * C;
    float v = xold[(size_t)perm[r] * C + c] * vals[r];
    short h = f2bf(v);
    Xh[t] = h;
    Xl[t] = f2bf(v - bf2f(h));
}

// G = (A+I)[perm,:] from bf16 A (small-int exact); zeroes rs_next
__global__ void gatherG_h(const short* __restrict__ A, int n,
                          const int* __restrict__ perm,
                          short* __restrict__ Gh, int kk,
                          float* __restrict__ rsz)
{
    int t = blockIdx.x * 256 + threadIdx.x;
    if (t < kk) rsz[t] = 0.f;
    if (t >= kk * n) return;
    int r = t / n, c = t - r * n;
    int pr = perm[r];
    float v = bf2f(A[(size_t)pr * n + c]) + (c == pr ? 1.f : 0.f);
    Gh[t] = f2bf(v);
}

__global__ void gatherG_hl(const short* __restrict__ Ahi, const short* __restrict__ Alo,
                           int n, const int* __restrict__ perm,
                           short* __restrict__ Gh, short* __restrict__ Gl, int kk,
                           float* __restrict__ rsz)
{
    int t = blockIdx.x * 256 + threadIdx.x;
    if (t < kk) rsz[t] = 0.f;
    if (t >= kk * n) return;
    int r = t / n, c = t - r * n;
    int pr = perm[r];
    float v = bf2f(Ahi[(size_t)pr * n + c]) + bf2f(Alo[(size_t)pr * n + c])
            + (c == pr ? 1.f : 0.f);
    short h = f2bf(v);
    Gh[t] = h;
    Gl[t] = f2bf(v - bf2f(h));
}

// streaming: A_next = sum of S full-square mirrored slices, diag zeroed,
// emit hi(/lo), wave-reduced rowsum atomics (rs pre-zeroed by gatherG)
template<bool LO>
__global__ void aug_finish(const float* __restrict__ Cp, int S, int kk,
                           short* __restrict__ Ahs, short* __restrict__ Als,
                           float* __restrict__ rs)
{
    int t = blockIdx.x * 256 + threadIdx.x;
    int r = t / kk, c = t - r * kk;
    size_t stride = (size_t)kk * kk;
    float v = 0.f;
    for (int s = 0; s < S; s++) v += Cp[t + s * stride];
    if (r == c) v = 0.f;
    short h = f2bf(v);
    Ahs[t] = h;
    if (LO) Als[t] = f2bf(v - bf2f(h));
    float ws = v;
    for (int off = 32; off; off >>= 1) ws += __shfl_down(ws, off);
    if ((threadIdx.x & 63) == 0) atomicAdd(&rs[r], ws);
}

// ---------------------------------------------------------------------------
// Host orchestration
// ---------------------------------------------------------------------------

extern "C" void kernel_launch(void* const* d_in, const int* in_sizes, int n_in,
                              void* d_out, int out_size, void* d_ws, size_t ws_size,
                              hipStream_t stream)
{
    const float* x0  = (const float*)d_in[0];
    const int*   ei  = (const int*)d_in[1];
    const float* Wd0 = (const float*)d_in[2];  const float* bd0 = (const float*)d_in[3];
    const float* Wd1 = (const float*)d_in[4];  const float* bd1 = (const float*)d_in[5];
    const float* Wd2 = (const float*)d_in[6];  const float* bd2 = (const float*)d_in[7];
    const float* Wd3 = (const float*)d_in[8];  const float* bd3 = (const float*)d_in[9];
    const float* p1  = (const float*)d_in[10];
    const float* p2  = (const float*)d_in[11];
    const float* p3  = (const float*)d_in[12];
    const float* Wu0 = (const float*)d_in[13]; const float* bu0 = (const float*)d_in[14];
    const float* Wu1 = (const float*)d_in[15]; const float* bu1 = (const float*)d_in[16];
    const float* Wu2 = (const float*)d_in[17]; const float* bu2 = (const float*)d_in[18];

    const int E = in_sizes[1] / 2;

    char* ws = (char*)d_ws;
    size_t off = 0;
    auto alloc = [&](size_t bytes) -> void* {
        void* p = ws + off;
        off += (bytes + 255) & ~(size_t)255;
        return p;
    };
    short* A0h  = (short*)alloc((size_t)4096 * 4096 * 2);
    short* A1h  = (short*)alloc((size_t)2048 * 2048 * 2);
    short* A2h  = (short*)alloc((size_t)1024 * 1024 * 2);
    short* A2l  = (short*)alloc((size_t)1024 * 1024 * 2);
    short* A3h  = (short*)alloc((size_t)512 * 512 * 2);
    short* A3l  = (short*)alloc((size_t)512 * 512 * 2);
    short* Gh   = (short*)alloc((size_t)2048 * 4096 * 2);
    short* Gl   = (short*)alloc((size_t)512 * 1024 * 2);
    float* Cp   = (float*)alloc((size_t)8 * 1024 * 1024 * 4);   // 32 MB partials
    float* xs0  = (float*)alloc((size_t)4096 * 256 * 4);
    float* xs1  = (float*)alloc((size_t)2048 * 256 * 4);
    float* xs2  = (float*)alloc((size_t)1024 * 256 * 4);
    short* xs0h = (short*)alloc((size_t)4096 * 256 * 2);
    short* xs0l = (short*)alloc((size_t)4096 * 256 * 2);
    short* xs1h = (short*)alloc((size_t)2048 * 256 * 2);
    short* xs1l = (short*)alloc((size_t)2048 * 256 * 2);
    short* xs2h = (short*)alloc((size_t)1024 * 256 * 2);
    short* xs2l = (short*)alloc((size_t)1024 * 256 * 2);
    float* xu0  = (float*)alloc((size_t)4096 * 256 * 4);
    float* xu1  = (float*)alloc((size_t)2048 * 256 * 4);
    float* xu2  = (float*)alloc((size_t)1024 * 256 * 4);
    short* xu0h = (short*)alloc((size_t)4096 * 256 * 2);
    short* xu0l = (short*)alloc((size_t)4096 * 256 * 2);
    short* xu1h = (short*)alloc((size_t)2048 * 256 * 2);
    short* xu1l = (short*)alloc((size_t)2048 * 256 * 2);
    short* xu2h = (short*)alloc((size_t)1024 * 256 * 2);
    short* xu2l = (short*)alloc((size_t)1024 * 256 * 2);
    short* X0h  = (short*)alloc((size_t)4096 * 128 * 2);
    short* X0l  = (short*)alloc((size_t)4096 * 128 * 2);
    short* xah  = (short*)alloc((size_t)2048 * 256 * 2);
    short* xal  = (short*)alloc((size_t)2048 * 256 * 2);
    short* Wth  = (short*)alloc((size_t)256 * 256 * 2);
    short* Wtl  = (short*)alloc((size_t)256 * 256 * 2);
    float* xwb  = (float*)alloc((size_t)4096 * 256 * 4);
    short* Zh   = (short*)alloc((size_t)256 * 4096 * 2);
    short* Zl   = (short*)alloc((size_t)256 * 4096 * 2);
    float* rs0  = (float*)alloc(4096 * 4);
    float* rs1  = (float*)alloc(2048 * 4);
    float* rs2  = (float*)alloc(1024 * 4);
    float* rs3  = (float*)alloc(512 * 4);
    float* scoreb = (float*)alloc(4096 * 4);
    float* valsb  = (float*)alloc(2048 * 4);
    int*   perm1  = (int*)alloc(2048 * 4);
    int*   perm2  = (int*)alloc(1024 * 4);
    int*   perm3  = (int*)alloc(512 * 4);

    // full GCN layer:
    //   Wt = split(W^T); xw,Z = gemm_bt<2,EPI2>(Xh,Xl,Wt);
    //   Cp = gemm_bt<mode,EPI0>(A, Z);  out = gcn_final(...)
    auto gcn = [&](const short* Xh, const short* Xl, int n, int Kc, int Cout,
                   const short* pAh, const short* pAl, const float* rsA,
                   const float* W, const float* b,
                   float* out, short* oh, short* ol, int relu, int modeA,
                   const int* perm) {
        wsplit<<<(Kc * Cout) / 256, 256, 0, stream>>>(W, Wth, Wtl, Kc, Cout);
        gemm_bt<2, 2><<<dim3(Cout / 128, n / 128, 1), 256, 0, stream>>>(
            Xh, Xl, Wth, Wtl, xwb, Zh, Zl, rsA, n, Cout, Kc, Kc);
        int S = (n == 4096) ? 4 : 8;
        dim3 g(Cout / 128, n / 128, S);
        if (modeA == 1)
            gemm_bt<1, 0><<<g, 256, 0, stream>>>(pAh, nullptr, Zh, Zl, Cp, nullptr, nullptr, nullptr, n, Cout, n, n / S);
        else
            gemm_bt<2, 0><<<g, 256, 0, stream>>>(pAh, pAl, Zh, Zl, Cp, nullptr, nullptr, nullptr, n, Cout, n, n / S);
        gcn_final<<<(n * Cout) / 256, 256, 0, stream>>>(
            Cp, S, xwb, rsA, b, out, oh, ol, n, Cout, relu, perm);
    };

    auto pool = [&](const float* xlev, int n, const float* p, int* perm) {
        int k = n / 2;
        score_kernel<<<n / 4, 256, 0, stream>>>(xlev, p, scoreb, n);
        rank_topk<<<n / 256, 256, 0, stream>>>(scoreb, n, k, perm, valsb);
        gather_x_hl<<<k * 2, 256, 0, stream>>>(xlev, perm, valsb, xah, xal, k * 256, 256);
    };

    // ---- build adjacency ----
    hipMemsetAsync(A0h, 0, (size_t)4096 * 4096 * 2, stream);
    build_adj_bf16<<<(E + 255) / 256, 256, 0, stream>>>(ei, E, A0h, 4096);
    rowsum_bf16<<<1024, 256, 0, stream>>>(A0h, 4096, rs0);

    // ---- down 0 ----
    split_rows<<<(4096 * 128) / 256, 256, 0, stream>>>(x0, X0h, X0l, 4096 * 128);
    gcn(X0h, X0l, 4096, 128, 256, A0h, nullptr, rs0, Wd0, bd0, xs0, xs0h, xs0l, 1, 1, nullptr);

    // ---- level 0 -> 1 ----
    pool(xs0, 4096, p1, perm1);
    gatherG_h<<<(2048 * 4096) / 256, 256, 0, stream>>>(A0h, 4096, perm1, Gh, 2048, rs1);
    gemm_bt<0, 1><<<dim3(16, 16, 2), 256, 0, stream>>>(Gh, nullptr, Gh, nullptr, Cp, nullptr, nullptr, nullptr, 2048, 2048, 4096, 2048);
    aug_finish<false><<<(2048 * 2048) / 256, 256, 0, stream>>>(Cp, 2, 2048, A1h, nullptr, rs1);
    gcn(xah, xal, 2048, 256, 256, A1h, nullptr, rs1, Wd1, bd1, xs1, xs1h, xs1l, 1, 1, nullptr);

    // ---- level 1 -> 2 ----
    pool(xs1, 2048, p2, perm2);
    gatherG_h<<<(1024 * 2048) / 256, 256, 0, stream>>>(A1h, 2048, perm2, Gh, 1024, rs2);
    gemm_bt<0, 1><<<dim3(8, 8, 8), 256, 0, stream>>>(Gh, nullptr, Gh, nullptr, Cp, nullptr, nullptr, nullptr, 1024, 1024, 2048, 256);
    aug_finish<true><<<(1024 * 1024) / 256, 256, 0, stream>>>(Cp, 8, 1024, A2h, A2l, rs2);
    gcn(xah, xal, 1024, 256, 256, A2h, A2l, rs2, Wd2, bd2, xs2, xs2h, xs2l, 1, 2, nullptr);

    // ---- level 2 -> 3 ----
    pool(xs2, 1024, p3, perm3);
    gatherG_hl<<<(512 * 1024) / 256, 256, 0, stream>>>(A2h, A2l, 1024, perm3, Gh, Gl, 512, rs3);
    gemm_bt<2, 1><<<dim3(4, 4, 8), 256, 0, stream>>>(Gh, Gl, Gh, Gl, Cp, nullptr, nullptr, nullptr, 512, 512, 1024, 128);
    aug_finish<true><<<(512 * 512) / 256, 256, 0, stream>>>(Cp, 8, 512, A3h, A3l, rs3);

    // ---- down 3, scattered into xu2 = xs2 + u ----
    hipMemcpyAsync(xu2,  xs2,  (size_t)1024 * 256 * 4, hipMemcpyDeviceToDevice, stream);
    hipMemcpyAsync(xu2h, xs2h, (size_t)1024 * 256 * 2, hipMemcpyDeviceToDevice, stream);
    hipMemcpyAsync(xu2l, xs2l, (size_t)1024 * 256 * 2, hipMemcpyDeviceToDevice, stream);
    gcn(xah, xal, 512, 256, 256, A3h, A3l, rs3, Wd3, bd3, xu2, xu2h, xu2l, 1, 2, perm3);

    // ---- up 0 (n=1024, A2), scattered into xu1 = xs1 + u ----
    hipMemcpyAsync(xu1,  xs1,  (size_t)2048 * 256 * 4, hipMemcpyDeviceToDevice, stream);
    hipMemcpyAsync(xu1h, xs1h, (size_t)2048 * 256 * 2, hipMemcpyDeviceToDevice, stream);
    hipMemcpyAsync(xu1l, xs1l, (size_t)2048 * 256 * 2, hipMemcpyDeviceToDevice, stream);
    gcn(xu2h, xu2l, 1024, 256, 256, A2h, A2l, rs2, Wu0, bu0, xu1, xu1h, xu1l, 1, 2, perm2);

    // ---- up 1 (n=2048, A1), scattered into xu0 = xs0 + u ----
    hipMemcpyAsync(xu0,  xs0,  (size_t)4096 * 256 * 4, hipMemcpyDeviceToDevice, stream);
    hipMemcpyAsync(xu0h, xs0h, (size_t)4096 * 256 * 2, hipMemcpyDeviceToDevice, stream);
    hipMemcpyAsync(xu0l, xs0l, (size_t)4096 * 256 * 2, hipMemcpyDeviceToDevice, stream);
    gcn(xu1h, xu1l, 2048, 256, 256, A1h, nullptr, rs1, Wu1, bu1, xu0, xu0h, xu0l, 1, 1, perm1);

    // ---- up 2 (n=4096, A0, Cout=128, no relu) -> d_out ----
    gcn(xu0h, xu0l, 4096, 256, 128, A0h, nullptr, rs0, Wu2, bu2, (float*)d_out, nullptr, nullptr, 0, 1, nullptr);
}

// Round 5
// 643.266 us; speedup vs baseline: 1.9570x; 1.0514x over previous
//
#include <hip/hip_runtime.h>

// ---------------------------------------------------------------------------
// GraphUNet on MI355X.  N=4096, IN_C=128, HID=256, OUT_C=128, DEPTH=3.
// Round-5: occupancy-driven split-K everywhere (>=512 blocks for big GEMMs),
// bf16 TRI partials (integer-exact), transposed xw partials + z_reduce,
// prep-fused weight splits, inv-perm-fused residual scatter.
// ---------------------------------------------------------------------------

typedef __attribute__((ext_vector_type(8))) short bf16x8;
typedef __attribute__((ext_vector_type(4))) float f32x4;

__device__ __forceinline__ short f2bf(float f) {
    unsigned u = __builtin_bit_cast(unsigned, f);
    u += 0x7FFFu + ((u >> 16) & 1u);          // RNE
    return (short)(u >> 16);
}
__device__ __forceinline__ float bf2f(short s) {
    unsigned u = ((unsigned)(unsigned short)s) << 16;
    return __builtin_bit_cast(float, u);
}

#define GLL16(gsrc, ldst)                                                        \
    __builtin_amdgcn_global_load_lds(                                            \
        (__attribute__((address_space(1))) void*)(gsrc),                         \
        (__attribute__((address_space(3))) void*)(ldst), 16, 0, 0)

// ---------------------------------------------------------------------------
// bf16 BT GEMM: C(MxN) = A(MxK) @ B^T, B stored N x K row-major.
// MODE 0: Ah@Bh ; 1: +Ah@Bl ; 2: +Al@Bh   (lo*lo dropped, ~2^-18 rel)
// EPI 0: fp32 partial slice [z][M][N]
// EPI 1: fp32 mirrored square slices (TRI: blocks by>bx exit)
// EPI 3: fp32 TRANSPOSED partial slice [z][N][M] (f32x4 stores)
// EPI 4: bf16 mirrored square slices (TRI; values integer-exact in bf16)
// ---------------------------------------------------------------------------
template<int MODE, int EPI>
__global__ __launch_bounds__(256, 2)
void gemm_bt(const short* __restrict__ Ah, const short* __restrict__ Al,
             const short* __restrict__ Bh, const short* __restrict__ Bl,
             float* __restrict__ Cf, int M, int N, int K, int kChunk)
{
    if ((EPI == 1 || EPI == 4) && (int)blockIdx.y > (int)blockIdx.x) return;

    __shared__ short sAh[128 * 32];
    __shared__ short sBh[128 * 32];
    __shared__ short sAl[(MODE == 2) ? 128 * 32 : 8];
    __shared__ short sBl[(MODE >= 1) ? 128 * 32 : 8];

    const int t    = threadIdx.x;
    const int lane = t & 63;
    const int wave = t >> 6;
    const int tM   = blockIdx.y * 128;
    const int tN   = blockIdx.x * 128;
    const int k0   = blockIdx.z * kChunk;

    const int wm  = (wave >> 1) * 64;
    const int wn  = (wave & 1) * 64;
    const int l15 = lane & 15;
    const int g8  = (lane >> 4) * 8;

    f32x4 acc[4][4];
    const f32x4 zero = {0.f, 0.f, 0.f, 0.f};
#pragma unroll
    for (int i = 0; i < 4; i++)
#pragma unroll
        for (int j = 0; j < 4; j++) acc[i][j] = zero;

    const int i0 = t, i1 = t + 256;
    const short* a0 = Ah + (size_t)(tM + (i0 >> 2)) * K + (i0 & 3) * 8;
    const short* a1 = Ah + (size_t)(tM + (i1 >> 2)) * K + (i1 & 3) * 8;
    const short* b0 = Bh + (size_t)(tN + (i0 >> 2)) * K + (i0 & 3) * 8;
    const short* b1 = Bh + (size_t)(tN + (i1 >> 2)) * K + (i1 & 3) * 8;
    const short *bl0 = nullptr, *bl1 = nullptr, *al0 = nullptr, *al1 = nullptr;
    if (MODE >= 1) {
        bl0 = Bl + (size_t)(tN + (i0 >> 2)) * K + (i0 & 3) * 8;
        bl1 = Bl + (size_t)(tN + (i1 >> 2)) * K + (i1 & 3) * 8;
    }
    if (MODE == 2) {
        al0 = Al + (size_t)(tM + (i0 >> 2)) * K + (i0 & 3) * 8;
        al1 = Al + (size_t)(tM + (i1 >> 2)) * K + (i1 & 3) * 8;
    }

    for (int kb = k0; kb < k0 + kChunk; kb += 32) {
        GLL16(a0 + kb, &sAh[i0 * 8]);
        GLL16(a1 + kb, &sAh[i1 * 8]);
        GLL16(b0 + kb, &sBh[i0 * 8]);
        GLL16(b1 + kb, &sBh[i1 * 8]);
        if (MODE >= 1) { GLL16(bl0 + kb, &sBl[i0 * 8]); GLL16(bl1 + kb, &sBl[i1 * 8]); }
        if (MODE == 2) { GLL16(al0 + kb, &sAl[i0 * 8]); GLL16(al1 + kb, &sAl[i1 * 8]); }
        __syncthreads();

        bf16x8 aF[4], bF[4], aL[4], bL[4];
#pragma unroll
        for (int i = 0; i < 4; i++)
            aF[i] = *(const bf16x8*)&sAh[(wm + i * 16 + l15) * 32 + g8];
#pragma unroll
        for (int j = 0; j < 4; j++)
            bF[j] = *(const bf16x8*)&sBh[(wn + j * 16 + l15) * 32 + g8];
        if (MODE >= 1)
#pragma unroll
            for (int j = 0; j < 4; j++)
                bL[j] = *(const bf16x8*)&sBl[(wn + j * 16 + l15) * 32 + g8];
        if (MODE == 2)
#pragma unroll
            for (int i = 0; i < 4; i++)
                aL[i] = *(const bf16x8*)&sAl[(wm + i * 16 + l15) * 32 + g8];

#pragma unroll
        for (int i = 0; i < 4; i++)
#pragma unroll
            for (int j = 0; j < 4; j++) {
                acc[i][j] = __builtin_amdgcn_mfma_f32_16x16x32_bf16(aF[i], bF[j], acc[i][j], 0, 0, 0);
                if (MODE >= 1)
                    acc[i][j] = __builtin_amdgcn_mfma_f32_16x16x32_bf16(aF[i], bL[j], acc[i][j], 0, 0, 0);
                if (MODE == 2)
                    acc[i][j] = __builtin_amdgcn_mfma_f32_16x16x32_bf16(aL[i], bF[j], acc[i][j], 0, 0, 0);
            }
        __syncthreads();
    }

    // C/D layout: col=lane&15, row=(lane>>4)*4+reg  [m89-verified]
    const int r4 = (lane >> 4) * 4;
    if (EPI == 3) {
        float* CT = Cf + (size_t)blockIdx.z * M * N;   // [N][M]
#pragma unroll
        for (int i = 0; i < 4; i++)
#pragma unroll
            for (int j = 0; j < 4; j++) {
                const int col   = tN + wn + j * 16 + l15;
                const int rbase = tM + wm + i * 16 + r4;
                *(f32x4*)&CT[(size_t)col * M + rbase] = acc[i][j];
            }
    } else if (EPI == 4) {
        short* Cg = (short*)Cf + (size_t)blockIdx.z * M * N;
#pragma unroll
        for (int i = 0; i < 4; i++)
#pragma unroll
            for (int j = 0; j < 4; j++) {
                const int col   = tN + wn + j * 16 + l15;
                const int rbase = tM + wm + i * 16 + r4;
#pragma unroll
                for (int r = 0; r < 4; r++)
                    Cg[(size_t)(rbase + r) * N + col] = f2bf(acc[i][j][r]);
            }
        if (tM != tN) {
#pragma unroll
            for (int i = 0; i < 4; i++)
#pragma unroll
                for (int j = 0; j < 4; j++) {
                    const int col   = tN + wn + j * 16 + l15;
                    const int rbase = tM + wm + i * 16 + r4;
                    unsigned h0 = (unsigned short)f2bf(acc[i][j][0]);
                    unsigned h1 = (unsigned short)f2bf(acc[i][j][1]);
                    unsigned h2 = (unsigned short)f2bf(acc[i][j][2]);
                    unsigned h3 = (unsigned short)f2bf(acc[i][j][3]);
                    uint2 p; p.x = h0 | (h1 << 16); p.y = h2 | (h3 << 16);
                    *(uint2*)&Cg[(size_t)col * N + rbase] = p;
                }
        }
    } else {
        float* Cg = Cf + (size_t)blockIdx.z * M * N;
#pragma unroll
        for (int i = 0; i < 4; i++)
#pragma unroll
            for (int j = 0; j < 4; j++) {
                const int col = tN + wn + j * 16 + l15;
                float* cp = Cg + (size_t)(tM + wm + i * 16 + r4) * N + col;
#pragma unroll
                for (int r = 0; r < 4; r++) cp[(size_t)r * N] = acc[i][j][r];
            }
        if (EPI == 1 && tM != tN) {
#pragma unroll
            for (int i = 0; i < 4; i++)
#pragma unroll
                for (int j = 0; j < 4; j++) {
                    const int col   = tN + wn + j * 16 + l15;
                    const int rbase = tM + wm + i * 16 + r4;
                    *(f32x4*)&Cg[(size_t)col * N + rbase] = acc[i][j];
                }
        }
    }
}

// ---------------------------------------------------------------------------
// Utility kernels
// ---------------------------------------------------------------------------

// one-shot prep: W^T hi/lo for all 7 layers + x0 hi/lo split
__global__ void prep(const float* __restrict__ Wd0, const float* __restrict__ Wd1,
                     const float* __restrict__ Wd2, const float* __restrict__ Wd3,
                     const float* __restrict__ Wu0, const float* __restrict__ Wu1,
                     const float* __restrict__ Wu2, const float* __restrict__ x0,
                     short* __restrict__ Wth, short* __restrict__ Wtl,
                     short* __restrict__ Xh, short* __restrict__ Xl)
{
    int t = blockIdx.x * 256 + threadIdx.x;
    float v; int dst;
    if (t < 32768)       { int e = t;          v = Wd0[e]; dst = 0      + (e & 255) * 128 + (e >> 8); }
    else if (t < 98304)  { int e = t - 32768;  v = Wd1[e]; dst = 32768  + (e & 255) * 256 + (e >> 8); }
    else if (t < 163840) { int e = t - 98304;  v = Wd2[e]; dst = 98304  + (e & 255) * 256 + (e >> 8); }
    else if (t < 229376) { int e = t - 163840; v = Wd3[e]; dst = 163840 + (e & 255) * 256 + (e >> 8); }
    else if (t < 294912) { int e = t - 229376; v = Wu0[e]; dst = 229376 + (e & 255) * 256 + (e >> 8); }
    else if (t < 360448) { int e = t - 294912; v = Wu1[e]; dst = 294912 + (e & 255) * 256 + (e >> 8); }
    else if (t < 393216) { int e = t - 360448; v = Wu2[e]; dst = 360448 + (e & 127) * 256 + (e >> 7); }
    else {
        int e = t - 393216;                      // x0: 4096*128
        v = x0[e];
        short h = f2bf(v);
        Xh[e] = h; Xl[e] = f2bf(v - bf2f(h));
        return;
    }
    short h = f2bf(v);
    Wth[dst] = h; Wtl[dst] = f2bf(v - bf2f(h));
}

__global__ void build_adj_bf16(const int* __restrict__ ei, int E,
                               short* __restrict__ A, int n)
{
    int e = blockIdx.x * 256 + threadIdx.x;
    if (e >= E) return;
    int i = ei[e], j = ei[E + e];
    if (i != j) {
        A[(size_t)i * n + j] = (short)0x3F80;
        A[(size_t)j * n + i] = (short)0x3F80;
    }
}

__global__ void rowsum_bf16(const short* __restrict__ A, int n,
                            float* __restrict__ rs)
{
    int row = blockIdx.x * 4 + (threadIdx.x >> 6);
    int lane = threadIdx.x & 63;
    const ushort4* ar = (const ushort4*)(A + (size_t)row * n);
    float s = 0.f;
    for (int c = lane; c < (n >> 2); c += 64) {
        ushort4 u = ar[c];
        s += bf2f((short)u.x) + bf2f((short)u.y) + bf2f((short)u.z) + bf2f((short)u.w);
    }
    for (int off = 32; off; off >>= 1) s += __shfl_down(s, off);
    if (lane == 0) rs[row] = s;
}

// reduce transposed xw partial slices -> Z^T hi/lo  (all coalesced)
__global__ void z_reduce(const float* __restrict__ Cp, int S,
                         const float* __restrict__ rs,
                         short* __restrict__ Zh, short* __restrict__ Zl,
                         int n, int C)
{
    int t = blockIdx.x * 256 + threadIdx.x;          // t = c*n + r
    int r = t % n;
    size_t stride = (size_t)n * C;
    float v = 0.f;
    for (int s = 0; s < S; s++) v += Cp[t + s * stride];
    float z = v / sqrtf(rs[r] + 2.f);
    short h = f2bf(z);
    Zh[t] = h;
    Zl[t] = f2bf(z - bf2f(h));
}

// fused: reduce AZ slices + GCN epilogue (+inv-perm residual scatter) + hi/lo
__global__ void gcn_final(const float* __restrict__ Cp, int S,
                          const short* __restrict__ Zh, const short* __restrict__ Zl,
                          const float* __restrict__ rs, const float* __restrict__ b,
                          float* __restrict__ out, short* __restrict__ oh,
                          short* __restrict__ ol, int k, int C, int relu,
                          const int* __restrict__ inv, const float* __restrict__ res)
{
    int t = blockIdx.x * 256 + threadIdx.x;
    int j = t / C, c = t - j * C;
    int r = inv ? inv[j] : j;
    float v = res ? res[t] : 0.f;
    if (r >= 0) {
        size_t base = (size_t)r * C + c;
        size_t stride = (size_t)k * C;
        float az = 0.f;
        for (int s = 0; s < S; s++) az += Cp[base + s * stride];
        float d = 1.f / sqrtf(rs[r] + 2.f);
        size_t zi = (size_t)c * k + r;
        float zz = bf2f(Zh[zi]) + bf2f(Zl[zi]);      // zz ~= d * xw
        float g = d * az + 2.f * d * zz + b[c];
        if (relu && g < 0.f) g = 0.f;
        v += g;
    }
    out[t] = v;
    if (oh) { short h = f2bf(v); oh[t] = h; ol[t] = f2bf(v - bf2f(h)); }
}

__global__ void score_kernel(const float* __restrict__ x,
                             const float* __restrict__ p,
                             float* __restrict__ score, int n)
{
    int row = blockIdx.x * 4 + (threadIdx.x >> 6);
    int lane = threadIdx.x & 63;
    float4 pv = ((const float4*)p)[lane];
    float4 xv = ((const float4*)(x + (size_t)row * 256))[lane];
    double nn  = (double)pv.x * pv.x + (double)pv.y * pv.y +
                 (double)pv.z * pv.z + (double)pv.w * pv.w;
    double acc = (double)xv.x * pv.x + (double)xv.y * pv.y +
                 (double)xv.z * pv.z + (double)xv.w * pv.w;
    for (int off = 32; off; off >>= 1) {
        acc += __shfl_down(acc, off);
        nn  += __shfl_down(nn, off);
    }
    if (lane == 0) score[row] = tanhf((float)(acc / sqrt(nn)));
}

__device__ __forceinline__ unsigned long long packkey(float s, int i) {
    unsigned u = __builtin_bit_cast(unsigned, s);
    u = (u & 0x80000000u) ? ~u : (u | 0x80000000u);
    return ((unsigned long long)u << 32) | (unsigned)(0xFFFFFFFFu - (unsigned)i);
}

__global__ __launch_bounds__(256)
void rank_topk(const float* __restrict__ score, int n, int k,
               int* __restrict__ perm, float* __restrict__ vals,
               int* __restrict__ inv)
{
    __shared__ unsigned long long sk[1024];
    int i = blockIdx.x * 256 + threadIdx.x;
    float s = score[i];
    unsigned long long mykey = packkey(s, i);
    int rank = 0;
    for (int jt = 0; jt < n; jt += 1024) {
#pragma unroll
        for (int q = 0; q < 4; q++) {
            int idx = jt + threadIdx.x + q * 256;
            sk[threadIdx.x + q * 256] = packkey(score[idx], idx);
        }
        __syncthreads();
#pragma unroll 16
        for (int q = 0; q < 1024; q++) rank += (sk[q] > mykey) ? 1 : 0;
        __syncthreads();
    }
    if (rank < k) { perm[rank] = i; vals[rank] = s; }
    inv[i] = (rank < k) ? rank : -1;
}

__global__ void gather_x_hl(const float* __restrict__ xold,
                            const int* __restrict__ perm,
                            const float* __restrict__ vals,
                            short* __restrict__ Xh, short* __restrict__ Xl,
                            int total, int C)
{
    int t = blockIdx.x * 256 + threadIdx.x;
    if (t >= total) return;
    int r = t / C, c = t - r * C;
    float v = xold[(size_t)perm[r] * C + c] * vals[r];
    short h = f2bf(v);
    Xh[t] = h;
    Xl[t] = f2bf(v - bf2f(h));
}

__global__ void gatherG_h(const short* __restrict__ A, int n,
                          const int* __restrict__ perm,
                          short* __restrict__ Gh, int kk,
                          float* __restrict__ rsz)
{
    int t = blockIdx.x * 256 + threadIdx.x;
    if (t < kk) rsz[t] = 0.f;
    if (t >= kk * n) return;
    int r = t / n, c = t - r * n;
    int pr = perm[r];
    float v = bf2f(A[(size_t)pr * n + c]) + (c == pr ? 1.f : 0.f);
    Gh[t] = f2bf(v);
}

__global__ void gatherG_hl(const short* __restrict__ Ahi, const short* __restrict__ Alo,
                           int n, const int* __restrict__ perm,
                           short* __restrict__ Gh, short* __restrict__ Gl, int kk,
                           float* __restrict__ rsz)
{
    int t = blockIdx.x * 256 + threadIdx.x;
    if (t < kk) rsz[t] = 0.f;
    if (t >= kk * n) return;
    int r = t / n, c = t - r * n;
    int pr = perm[r];
    float v = bf2f(Ahi[(size_t)pr * n + c]) + bf2f(Alo[(size_t)pr * n + c])
            + (c == pr ? 1.f : 0.f);
    short h = f2bf(v);
    Gh[t] = h;
    Gl[t] = f2bf(v - bf2f(h));
}

// bf16 mirrored slices -> A (integer-exact), rowsum atomics (rs pre-zeroed)
__global__ void aug_finish_h(const short* __restrict__ Cp, int S, int kk,
                             short* __restrict__ Ahs, float* __restrict__ rs)
{
    int t = blockIdx.x * 256 + threadIdx.x;
    int r = t / kk, c = t - r * kk;
    size_t stride = (size_t)kk * kk;
    float v = 0.f;
    for (int s = 0; s < S; s++) v += bf2f(Cp[t + s * stride]);
    if (r == c) v = 0.f;
    Ahs[t] = f2bf(v);
    float ws = v;
    for (int off = 32; off; off >>= 1) ws += __shfl_down(ws, off);
    if ((threadIdx.x & 63) == 0) atomicAdd(&rs[r], ws);
}

template<bool LO>
__global__ void aug_finish_f(const float* __restrict__ Cp, int S, int kk,
                             short* __restrict__ Ahs, short* __restrict__ Als,
                             float* __restrict__ rs)
{
    int t = blockIdx.x * 256 + threadIdx.x;
    int r = t / kk, c = t - r * kk;
    size_t stride = (size_t)kk * kk;
    float v = 0.f;
    for (int s = 0; s < S; s++) v += Cp[t + s * stride];
    if (r == c) v = 0.f;
    short h = f2bf(v);
    Ahs[t] = h;
    if (LO) Als[t] = f2bf(v - bf2f(h));
    float ws = v;
    for (int off = 32; off; off >>= 1) ws += __shfl_down(ws, off);
    if ((threadIdx.x & 63) == 0) atomicAdd(&rs[r], ws);
}

// ---------------------------------------------------------------------------
// Host orchestration
// ---------------------------------------------------------------------------

extern "C" void kernel_launch(void* const* d_in, const int* in_sizes, int n_in,
                              void* d_out, int out_size, void* d_ws, size_t ws_size,
                              hipStream_t stream)
{
    const float* x0  = (const float*)d_in[0];
    const int*   ei  = (const int*)d_in[1];
    const float* Wd0 = (const float*)d_in[2];  const float* bd0 = (const float*)d_in[3];
    const float* Wd1 = (const float*)d_in[4];  const float* bd1 = (const float*)d_in[5];
    const float* Wd2 = (const float*)d_in[6];  const float* bd2 = (const float*)d_in[7];
    const float* Wd3 = (const float*)d_in[8];  const float* bd3 = (const float*)d_in[9];
    const float* p1  = (const float*)d_in[10];
    const float* p2  = (const float*)d_in[11];
    const float* p3  = (const float*)d_in[12];
    const float* Wu0 = (const float*)d_in[13]; const float* bu0 = (const float*)d_in[14];
    const float* Wu1 = (const float*)d_in[15]; const float* bu1 = (const float*)d_in[16];
    const float* Wu2 = (const float*)d_in[17]; const float* bu2 = (const float*)d_in[18];

    const int E = in_sizes[1] / 2;

    char* ws = (char*)d_ws;
    size_t off = 0;
    auto alloc = [&](size_t bytes) -> void* {
        void* p = ws + off;
        off += (bytes + 255) & ~(size_t)255;
        return p;
    };
    short* A0h  = (short*)alloc((size_t)4096 * 4096 * 2);
    short* A1h  = (short*)alloc((size_t)2048 * 2048 * 2);
    short* A2h  = (short*)alloc((size_t)1024 * 1024 * 2);
    short* A2l  = (short*)alloc((size_t)1024 * 1024 * 2);
    short* A3h  = (short*)alloc((size_t)512 * 512 * 2);
    short* A3l  = (short*)alloc((size_t)512 * 512 * 2);
    short* Gh   = (short*)alloc((size_t)2048 * 4096 * 2);
    short* Gl   = (short*)alloc((size_t)512 * 1024 * 2);
    float* Cp   = (float*)alloc((size_t)40 * 1024 * 1024);   // 40 MB partial arena
    float* xs0  = (float*)alloc((size_t)4096 * 256 * 4);
    float* xs1  = (float*)alloc((size_t)2048 * 256 * 4);
    float* xs2  = (float*)alloc((size_t)1024 * 256 * 4);
    float* xu0  = (float*)alloc((size_t)4096 * 256 * 4);
    float* xu1  = (float*)alloc((size_t)2048 * 256 * 4);
    float* xu2  = (float*)alloc((size_t)1024 * 256 * 4);
    short* xu0h = (short*)alloc((size_t)4096 * 256 * 2);
    short* xu0l = (short*)alloc((size_t)4096 * 256 * 2);
    short* xu1h = (short*)alloc((size_t)2048 * 256 * 2);
    short* xu1l = (short*)alloc((size_t)2048 * 256 * 2);
    short* xu2h = (short*)alloc((size_t)1024 * 256 * 2);
    short* xu2l = (short*)alloc((size_t)1024 * 256 * 2);
    short* X0h  = (short*)alloc((size_t)4096 * 128 * 2);
    short* X0l  = (short*)alloc((size_t)4096 * 128 * 2);
    short* xah  = (short*)alloc((size_t)2048 * 256 * 2);
    short* xal  = (short*)alloc((size_t)2048 * 256 * 2);
    short* Wth  = (short*)alloc((size_t)393216 * 2);
    short* Wtl  = (short*)alloc((size_t)393216 * 2);
    short* Zh   = (short*)alloc((size_t)256 * 4096 * 2);
    short* Zl   = (short*)alloc((size_t)256 * 4096 * 2);
    float* rs0  = (float*)alloc(4096 * 4);
    float* rs1  = (float*)alloc(2048 * 4);
    float* rs2  = (float*)alloc(1024 * 4);
    float* rs3  = (float*)alloc(512 * 4);
    float* scoreb = (float*)alloc(4096 * 4);
    float* valsb  = (float*)alloc(2048 * 4);
    int*   perm1  = (int*)alloc(2048 * 4);
    int*   perm2  = (int*)alloc(1024 * 4);
    int*   perm3  = (int*)alloc(512 * 4);
    int*   inv1   = (int*)alloc(4096 * 4);
    int*   inv2   = (int*)alloc(2048 * 4);
    int*   inv3   = (int*)alloc(1024 * 4);

    // full GCN layer: x@W (split-K, transposed partials) -> z_reduce ->
    // A@Z (split-K) -> gcn_final (reduce + epilogue + optional inv-scatter)
    auto gcn = [&](const short* Xh, const short* Xl, int n, int Kc, int Cout,
                   const short* pAh, const short* pAl, const float* rsA,
                   int wtoff, const float* b,
                   float* out, short* oh, short* ol, int relu, int modeA,
                   int Saz, const int* inv, const float* res, int nout) {
        int Sxw = 4;
        gemm_bt<2, 3><<<dim3(Cout / 128, n / 128, Sxw), 256, 0, stream>>>(
            Xh, Xl, Wth + wtoff, Wtl + wtoff, Cp, n, Cout, Kc, Kc / Sxw);
        z_reduce<<<(n * Cout) / 256, 256, 0, stream>>>(Cp, Sxw, rsA, Zh, Zl, n, Cout);
        dim3 g(Cout / 128, n / 128, Saz);
        if (modeA == 1)
            gemm_bt<1, 0><<<g, 256, 0, stream>>>(pAh, nullptr, Zh, Zl, Cp, n, Cout, n, n / Saz);
        else
            gemm_bt<2, 0><<<g, 256, 0, stream>>>(pAh, pAl, Zh, Zl, Cp, n, Cout, n, n / Saz);
        gcn_final<<<(nout * Cout) / 256, 256, 0, stream>>>(
            Cp, Saz, Zh, Zl, rsA, b, out, oh, ol, n, Cout, relu, inv, res);
    };

    auto pool = [&](const float* xlev, int n, const float* p, int* perm, int* inv) {
        int k = n / 2;
        score_kernel<<<n / 4, 256, 0, stream>>>(xlev, p, scoreb, n);
        rank_topk<<<n / 256, 256, 0, stream>>>(scoreb, n, k, perm, valsb, inv);
        gather_x_hl<<<k, 256, 0, stream>>>(xlev, perm, valsb, xah, xal, k * 256, 256);
    };

    // ---- prep + adjacency ----
    prep<<<3584, 256, 0, stream>>>(Wd0, Wd1, Wd2, Wd3, Wu0, Wu1, Wu2, x0,
                                   Wth, Wtl, X0h, X0l);
    hipMemsetAsync(A0h, 0, (size_t)4096 * 4096 * 2, stream);
    build_adj_bf16<<<(E + 255) / 256, 256, 0, stream>>>(ei, E, A0h, 4096);
    rowsum_bf16<<<1024, 256, 0, stream>>>(A0h, 4096, rs0);

    // ---- down 0 ----
    gcn(X0h, X0l, 4096, 128, 256, A0h, nullptr, rs0, 0, bd0,
        xs0, nullptr, nullptr, 1, 1, 8, nullptr, nullptr, 4096);

    // ---- level 0 -> 1 ----
    pool(xs0, 4096, p1, perm1, inv1);
    gatherG_h<<<(2048 * 4096) / 256, 256, 0, stream>>>(A0h, 4096, perm1, Gh, 2048, rs1);
    gemm_bt<0, 4><<<dim3(16, 16, 4), 256, 0, stream>>>(Gh, nullptr, Gh, nullptr, Cp, 2048, 2048, 4096, 1024);
    aug_finish_h<<<(2048 * 2048) / 256, 256, 0, stream>>>((const short*)Cp, 4, 2048, A1h, rs1);
    gcn(xah, xal, 2048, 256, 256, A1h, nullptr, rs1, 32768, bd1,
        xs1, nullptr, nullptr, 1, 1, 16, nullptr, nullptr, 2048);

    // ---- level 1 -> 2 ----
    pool(xs1, 2048, p2, perm2, inv2);
    gatherG_h<<<(1024 * 2048) / 256, 256, 0, stream>>>(A1h, 2048, perm2, Gh, 1024, rs2);
    gemm_bt<0, 1><<<dim3(8, 8, 8), 256, 0, stream>>>(Gh, nullptr, Gh, nullptr, Cp, 1024, 1024, 2048, 256);
    aug_finish_f<true><<<(1024 * 1024) / 256, 256, 0, stream>>>(Cp, 8, 1024, A2h, A2l, rs2);
    gcn(xah, xal, 1024, 256, 256, A2h, A2l, rs2, 98304, bd2,
        xs2, nullptr, nullptr, 1, 2, 8, nullptr, nullptr, 1024);

    // ---- level 2 -> 3 ----
    pool(xs2, 1024, p3, perm3, inv3);
    gatherG_hl<<<(512 * 1024) / 256, 256, 0, stream>>>(A2h, A2l, 1024, perm3, Gh, Gl, 512, rs3);
    gemm_bt<2, 1><<<dim3(4, 4, 8), 256, 0, stream>>>(Gh, Gl, Gh, Gl, Cp, 512, 512, 1024, 128);
    aug_finish_f<true><<<(512 * 512) / 256, 256, 0, stream>>>(Cp, 8, 512, A3h, A3l, rs3);

    // ---- down 3: out scattered into xu2 = xs2 + u (inv3) ----
    gcn(xah, xal, 512, 256, 256, A3h, A3l, rs3, 163840, bd3,
        xu2, xu2h, xu2l, 1, 2, 8, inv3, xs2, 1024);

    // ---- up 0: out scattered into xu1 = xs1 + u (inv2) ----
    gcn(xu2h, xu2l, 1024, 256, 256, A2h, A2l, rs2, 229376, bu0,
        xu1, xu1h, xu1l, 1, 2, 8, inv2, xs1, 2048);

    // ---- up 1: out scattered into xu0 = xs0 + u (inv1) ----
    gcn(xu1h, xu1l, 2048, 256, 256, A1h, nullptr, rs1, 294912, bu1,
        xu0, xu0h, xu0l, 1, 1, 16, inv1, xs0, 4096);

    // ---- up 2 (final, Cout=128, no relu) -> d_out ----
    gcn(xu0h, xu0l, 4096, 256, 128, A0h, nullptr, rs0, 360448, bu2,
        (float*)d_out, nullptr, nullptr, 0, 1, 16, nullptr, nullptr, 4096);
}